// Round 5
// baseline (436.886 us; speedup 1.0000x reference)
//
#include <hip/hip_runtime.h>
#include <hip/hip_cooperative_groups.h>
#include <math.h>
#include <stdint.h>

namespace cg = cooperative_groups;

// B=8, S=2048, D=512 single-head self-attention, fp32 in/out, fp16 MFMA inside.
// Round 12: ONE cooperative persistent kernel (512 blocks x 256 thr = 2/CU),
// grid.sync() between stages, replacing 4 serialized dispatches.
//   Rationale: r0-r4 sum-of-kernels ~= 145us vs 211us wall -> ~60us of
//   dispatch boundaries (launch + drain + cross-XCD L2 acquire/release),
//   the largest cost after scores itself. Stage bodies and the r4 GEMM core
//   (128x128, 2-phase m201-style, 2-deep prefetch, vmcnt(6), 64KB dbuf LDS,
//   0 bank conflicts) are reused verbatim; only block->unit decode changes.
//   unit == bid (mod 8) everywhere -> XCD pinning preserved; a block keeps
//   its batch across stages -> L2 reuse improves.
//   Runtime fallback to the r4 four-kernel path if cooperative launch fails.
//
//  stage0 prep:   Xh = fp16(x);  W*T = fp16(W^T) for q,k,v      (22 units/blk)
//  stage1 proj:   z=0: Qh=(Xh.Wq+bq)/sqrt(512)  z=1: Kh=Xh.Wk+bk
//                 z=2: Vt[b][d][s] = (Xh.Wv+bv)^T                (3 units/blk)
//  stage2 scores: P[b] = fp16(exp(Qh.Kh^T)) UNNORMALIZED         (4 units/blk)
//  stage3 av:     out = (P.V)*mask/rowsum(P), rowsum via fdot2   (1 unit/blk)

typedef _Float16 f16x8 __attribute__((ext_vector_type(8)));
typedef _Float16 f16x4 __attribute__((ext_vector_type(4)));
typedef _Float16 f16x2 __attribute__((ext_vector_type(2)));
typedef float f32x4 __attribute__((ext_vector_type(4)));

__device__ __forceinline__ void async16(const _Float16* g, _Float16* l) {
    __builtin_amdgcn_global_load_lds(
        (const __attribute__((address_space(1))) unsigned int*)(uintptr_t)g,
        (__attribute__((address_space(3))) unsigned int*)(unsigned int)(uintptr_t)l,
        16, 0, 0);
}

__device__ __forceinline__ float frag_sum8(f16x8 v, float acc) {
#if __has_builtin(__builtin_amdgcn_fdot2)
    const f16x2 one2 = {(_Float16)1.f, (_Float16)1.f};
    const f16x2* p = (const f16x2*)&v;
    acc = __builtin_amdgcn_fdot2(p[0], one2, acc, false);
    acc = __builtin_amdgcn_fdot2(p[1], one2, acc, false);
    acc = __builtin_amdgcn_fdot2(p[2], one2, acc, false);
    acc = __builtin_amdgcn_fdot2(p[3], one2, acc, false);
#else
#pragma unroll
    for (int j = 0; j < 8; j++) acc += (float)v[j];
#endif
    return acc;
}

#define MFMA16(a, b, c) __builtin_amdgcn_mfma_f32_16x16x32_f16(a, b, c, 0, 0, 0)
#define BAR() __builtin_amdgcn_s_barrier()
#define LGKM0() asm volatile("s_waitcnt lgkmcnt(0)" ::: "memory")

// ---------------------------------------------------------------------------
// core: acc[4][4] += A[row0:+128][0:K] . B[col0:+128][0:K]^T, BK=64, 4 waves.
// (verbatim r4: m201-style phases, 2-deep prefetch, vmcnt(6), 64KB dbuf)
// ---------------------------------------------------------------------------
template <int NT, bool WITH_RS>
__device__ __forceinline__ void core128sq(
    const _Float16* __restrict__ A, const _Float16* __restrict__ B,
    int ld, int row0, int col0, _Float16* sm, f32x4 acc[4][4], float rs[4])
{
    const int tid = threadIdx.x, lane = tid & 63, wave = tid >> 6;
    const int wm = wave >> 1, wn = wave & 1;
    const int rc = lane >> 3;
    const int swz = ((lane & 7) ^ rc) * 8;
    const int fr = lane & 15, q = lane >> 4, fx = fr & 7;
    const size_t laneoff = (size_t)rc * ld + swz;

    const _Float16* gA[4]; int lA[4];
#pragma unroll
    for (int i = 0; i < 4; i++) {
        int c = wave * 4 + i;                        // A chunks 0..15
        gA[i] = A + (size_t)(row0 + 8 * c) * ld + laneoff;
        lA[i] = c * 512;
    }
    const _Float16* gBe[2]; const _Float16* gBl[2]; int lBe[2], lBl[2];
#pragma unroll
    for (int i = 0; i < 2; i++) {
        int idx = wave * 2 + i;                      // 0..7
        int je = (idx & 3) + (idx >> 2) * 8;         // early {0-3,8-11}
        int jl = je + 4;                             // late  {4-7,12-15}
        gBe[i] = B + (size_t)(col0 + 8 * je) * ld + laneoff;
        gBl[i] = B + (size_t)(col0 + 8 * jl) * ld + laneoff;
        lBe[i] = 8192 + je * 512;
        lBl[i] = 8192 + jl * 512;
    }

    // prologue: tile0 full (8/wave), tile1 A+Bearly (6/wave); vmcnt(6)=t0 done
#pragma unroll
    for (int i = 0; i < 4; i++) async16(gA[i], sm + lA[i]);
#pragma unroll
    for (int i = 0; i < 2; i++) async16(gBe[i], sm + lBe[i]);
#pragma unroll
    for (int i = 0; i < 2; i++) async16(gBl[i], sm + lBl[i]);
#pragma unroll
    for (int i = 0; i < 4; i++) async16(gA[i] + 64, sm + 16384 + lA[i]);
#pragma unroll
    for (int i = 0; i < 2; i++) async16(gBe[i] + 64, sm + 16384 + lBe[i]);
    asm volatile("s_waitcnt vmcnt(6)" ::: "memory");
    BAR();

#pragma unroll 2
    for (int t = 0; t < NT; ++t) {
        const _Float16* As = sm + (t & 1) * 16384;
        const _Float16* Bs = As + 8192;
        f16x8 af[4][2], b0f[2][2], b1f[2][2];

        // ---- P0: read A + B-early; stage t+1's B-late into the other buffer
#pragma unroll
        for (int m = 0; m < 4; m++)
#pragma unroll
            for (int s = 0; s < 2; s++) {
                int ra = wm * 64 + m * 16 + fr;
                af[m][s] = *(const f16x8*)&As[ra * 64 + (((s * 4 + q) ^ fx) * 8)];
            }
#pragma unroll
        for (int n = 0; n < 2; n++)
#pragma unroll
            for (int s = 0; s < 2; s++) {
                int rb = wn * 64 + n * 16 + fr;
                b0f[n][s] = *(const f16x8*)&Bs[rb * 64 + (((s * 4 + q) ^ fx) * 8)];
            }
        if (t + 1 < NT) {
            _Float16* nb = sm + ((t + 1) & 1) * 16384;
#pragma unroll
            for (int i = 0; i < 2; i++)
                async16(gBl[i] + (t + 1) * 64, nb + lBl[i]);
        }
        BAR(); LGKM0();
        if (WITH_RS) {
#pragma unroll
            for (int m = 0; m < 4; m++)
#pragma unroll
                for (int s = 0; s < 2; s++) rs[m] = frag_sum8(af[m][s], rs[m]);
        }
        __builtin_amdgcn_s_setprio(1);
#pragma unroll
        for (int s = 0; s < 2; s++)
#pragma unroll
            for (int m = 0; m < 4; m++)
#pragma unroll
                for (int n = 0; n < 2; n++)
                    acc[m][n] = MFMA16(af[m][s], b0f[n][s], acc[m][n]);
        __builtin_amdgcn_s_setprio(0);
        BAR();

        // ---- P1: read B-late; stage t+2's A+B-early into this buffer
#pragma unroll
        for (int n = 0; n < 2; n++)
#pragma unroll
            for (int s = 0; s < 2; s++) {
                int rb = wn * 64 + (2 + n) * 16 + fr;
                b1f[n][s] = *(const f16x8*)&Bs[rb * 64 + (((s * 4 + q) ^ fx) * 8)];
            }
        if (t + 2 < NT) {
            _Float16* stg = sm + (t & 1) * 16384;
            const int k2 = (t + 2) * 64;
#pragma unroll
            for (int i = 0; i < 4; i++) async16(gA[i] + k2, stg + lA[i]);
#pragma unroll
            for (int i = 0; i < 2; i++) async16(gBe[i] + k2, stg + lBe[i]);
            asm volatile("s_waitcnt vmcnt(6)" ::: "memory");   // t+1 landed
        } else {
            asm volatile("s_waitcnt vmcnt(0)" ::: "memory");   // tail drain
        }
        BAR(); LGKM0();
        __builtin_amdgcn_s_setprio(1);
#pragma unroll
        for (int s = 0; s < 2; s++)
#pragma unroll
            for (int m = 0; m < 4; m++)
#pragma unroll
                for (int n = 0; n < 2; n++)
                    acc[m][2 + n] = MFMA16(af[m][s], b1f[n][s], acc[m][2 + n]);
        __builtin_amdgcn_s_setprio(0);
        BAR();
    }
}

// --------------------------- stage unit bodies ------------------------------
__device__ __forceinline__ void prep_unit(
    int u, const float* __restrict__ x,
    const float* __restrict__ Wq, const float* __restrict__ Wk,
    const float* __restrict__ Wv,
    _Float16* Xh, _Float16* WqT, _Float16* WkT, _Float16* WvT)
{
    const int tid = threadIdx.x;
    if (u < 8192) {                         // convert x: 8.4M elems / 1024
        int i = (u * 256 + tid) * 4;
        float4 v = *(const float4*)(x + i);
        f16x4 h;
        h.x = (_Float16)v.x; h.y = (_Float16)v.y;
        h.z = (_Float16)v.z; h.w = (_Float16)v.w;
        *(f16x4*)&Xh[i] = h;
    } else {                                // transpose W: 3 x 1024 units
        int t = u - 8192;
        int z = t >> 10;
        const float* W = (z == 0) ? Wq : (z == 1) ? Wk : Wv;
        _Float16* Wt   = (z == 0) ? WqT : (z == 1) ? WkT : WvT;
        int idx = (t & 1023) * 256 + tid;
        int n = idx >> 9, k = idx & 511;
        Wt[idx] = (_Float16)W[k * 512 + n];
    }
}

// proj unit u in [0,1536): bx = u&127, by = (u>>7)&3, z = u>>9
__device__ __forceinline__ void proj_unit(
    int u, const _Float16* Xh,
    const _Float16* WqT, const float* __restrict__ bq,
    const _Float16* WkT, const float* __restrict__ bk,
    const _Float16* WvT, const float* __restrict__ bv,
    _Float16* Qh, _Float16* Kh, _Float16* Vt, _Float16* smem)
{
    const int bx = u & 127, by = (u >> 7) & 3, z = u >> 9;
    f32x4 acc[4][4];
#pragma unroll
    for (int i = 0; i < 4; i++)
#pragma unroll
        for (int j = 0; j < 4; j++) acc[i][j] = (f32x4){0.f, 0.f, 0.f, 0.f};
    float rs_unused[4];

    const int lane = threadIdx.x & 63, wave = threadIdx.x >> 6;
    const int wm = wave >> 1, wn = wave & 1;
    const int er = (lane >> 4) * 4, ec = lane & 15;  // C/D: col=lane&15

    if (z < 2) {
        const _Float16* Wt = (z == 0) ? WqT : WkT;
        const float* bias  = (z == 0) ? bq : bk;
        _Float16* P        = (z == 0) ? Qh : Kh;
        const float sc     = (z == 0) ? 0.04419417382415922f : 1.0f;
        const int row0 = bx * 128, col0 = by * 128;
        core128sq<8, false>(Xh, Wt, 512, row0, col0, smem, acc, rs_unused);
#pragma unroll
        for (int tm = 0; tm < 4; tm++)
#pragma unroll
            for (int tn = 0; tn < 4; tn++) {
                int col = col0 + wn * 64 + tn * 16 + ec;
                float bb = bias[col];
#pragma unroll
                for (int r = 0; r < 4; r++) {
                    int row = row0 + wm * 64 + tm * 16 + er + r;
                    P[(size_t)row * 512 + col] = (_Float16)((acc[tm][tn][r] + bb) * sc);
                }
            }
    } else {
        // transposed V: out(row=d, col=s_global) = sum_k WvT[d][k] * Xh[s][k]
        const int row0 = by * 128;           // d (M=512)
        const int col0 = bx * 128;           // s_global (N=16384)
        core128sq<8, false>(WvT, Xh, 512, row0, col0, smem, acc, rs_unused);
#pragma unroll
        for (int tm = 0; tm < 4; tm++)
#pragma unroll
            for (int tn = 0; tn < 4; tn++) {
                int col = col0 + wn * 64 + tn * 16 + ec;   // s_global
                size_t obase = (size_t)(col >> 11) * (512 * 2048) + (col & 2047);
#pragma unroll
                for (int r = 0; r < 4; r++) {
                    int row = row0 + wm * 64 + tm * 16 + er + r;  // d
                    Vt[obase + (size_t)row * 2048] = (_Float16)(acc[tm][tn][r] + bv[row]);
                }
            }
    }
}

// scores unit u in [0,2048): b=u&7, rem=u>>3, col0=(rem&15)*128, row0=(rem>>4)*128
__device__ __forceinline__ void scores_unit(
    int u, const _Float16* Qh, const _Float16* Kh, _Float16* Sh,
    _Float16* smem)
{
    const int b   = u & 7;
    const int rem = u >> 3;
    const int col0 = (rem & 15) * 128;
    const int row0 = (rem >> 4) * 128;

    const _Float16* A = Qh + (size_t)b * 2048 * 512;
    const _Float16* B = Kh + (size_t)b * 2048 * 512;
    _Float16* S = Sh + (size_t)b * 2048 * 2048;

    f32x4 acc[4][4];
#pragma unroll
    for (int i = 0; i < 4; i++)
#pragma unroll
        for (int j = 0; j < 4; j++) acc[i][j] = (f32x4){0.f, 0.f, 0.f, 0.f};
    float rs_unused[4];

    core128sq<8, false>(A, B, 512, row0, col0, smem, acc, rs_unused);

    const int lane = threadIdx.x & 63, wave = threadIdx.x >> 6;
    const int wm = wave >> 1, wn = wave & 1;
    const int er = (lane >> 4) * 4, ec = lane & 15;
#pragma unroll
    for (int tm = 0; tm < 4; tm++)
#pragma unroll
        for (int tn = 0; tn < 4; tn++) {
            int col = col0 + wn * 64 + tn * 16 + ec;
#pragma unroll
            for (int r = 0; r < 4; r++) {
                int row = row0 + wm * 64 + tm * 16 + er + r;
                S[(size_t)row * 2048 + col] = (_Float16)__expf(acc[tm][tn][r]);
            }
        }
}

// av unit u in [0,512): b=u&7, rem=u>>3, col0=(rem&3)*128, row0=(rem>>2)*128
__device__ __forceinline__ void av_unit(
    int u, const _Float16* Sh, const _Float16* Vt,
    const float* __restrict__ mask, float* __restrict__ out, _Float16* smem)
{
    const int b   = u & 7;
    const int rem = u >> 3;
    const int col0 = (rem & 3) * 128;
    const int row0 = (rem >> 2) * 128;

    const _Float16* A = Sh + (size_t)b * 2048 * 2048;
    const _Float16* B = Vt + (size_t)b * 512 * 2048;
    float* O = out + (size_t)b * 2048 * 512;
    const float* mk = mask + (size_t)b * 2048;

    f32x4 acc[4][4];
#pragma unroll
    for (int i = 0; i < 4; i++)
#pragma unroll
        for (int j = 0; j < 4; j++) acc[i][j] = (f32x4){0.f, 0.f, 0.f, 0.f};
    float rs[4] = {0.f, 0.f, 0.f, 0.f};

    core128sq<32, true>(A, B, 2048, row0, col0, smem, acc, rs);

    const int lane = threadIdx.x & 63, wave = threadIdx.x >> 6;
    const int wm = wave >> 1, wn = wave & 1;
    const int er = (lane >> 4) * 4, ec = lane & 15;

#pragma unroll
    for (int tm = 0; tm < 4; tm++) {
        rs[tm] += __shfl_xor(rs[tm], 16, 64);
        rs[tm] += __shfl_xor(rs[tm], 32, 64);
    }
    __syncthreads();                       // all waves out of the GEMM loop
    float* l_s = (float*)smem;             // alias dead staging LDS
    if (wn == 0 && lane < 16) {
#pragma unroll
        for (int tm = 0; tm < 4; tm++) l_s[wm * 64 + tm * 16 + lane] = rs[tm];
    }
    __syncthreads();

#pragma unroll
    for (int tm = 0; tm < 4; tm++)
#pragma unroll
        for (int r = 0; r < 4; r++) {
            int lrow = wm * 64 + tm * 16 + er + r;
            int row = row0 + lrow;
            float s = mk[row] / l_s[lrow];
#pragma unroll
            for (int tn = 0; tn < 4; tn++) {
                int col = col0 + wn * 64 + tn * 16 + ec;
                O[(size_t)row * 512 + col] = acc[tm][tn][r] * s;
            }
        }
}

// --------------------------- fused cooperative kernel -----------------------
// NOTE: Xh and Sh alias the same workspace (Xh dead after stage1) -> no
// __restrict__ on them.
__global__ __launch_bounds__(256, 2) void fused_all(
    const float* __restrict__ x, const float* __restrict__ mask,
    const float* __restrict__ Wq, const float* __restrict__ bq,
    const float* __restrict__ Wk, const float* __restrict__ bk,
    const float* __restrict__ Wv, const float* __restrict__ bv,
    float* __restrict__ out,
    _Float16* Qh, _Float16* Kh, _Float16* Vt,
    _Float16* WqT, _Float16* WkT, _Float16* WvT,
    _Float16* Xh, _Float16* Sh)
{
    __shared__ __align__(16) _Float16 smem[2 * 16384];
    cg::grid_group grid = cg::this_grid();
    const int bid = blockIdx.x;            // 0..511; bid&7 ~ XCD

    // stage 0: prep (11264 units, 22/block, uniform)
    for (int u = bid; u < 11264; u += 512)
        prep_unit(u, x, Wq, Wk, Wv, Xh, WqT, WkT, WvT);
    grid.sync();
    // stage 1: proj (1536 units, 3/block: same (bx,by) for z=0,1,2 -> Xh tile
    // stays in this XCD's L2 across all three projections)
    for (int u = bid; u < 1536; u += 512)
        proj_unit(u, Xh, WqT, bq, WkT, bk, WvT, bv, Qh, Kh, Vt, smem);
    grid.sync();
    // stage 2: scores (2048 units, 4/block; u == bid mod 8 -> batch pinned)
    for (int u = bid; u < 2048; u += 512)
        scores_unit(u, Qh, Kh, Sh, smem);
    grid.sync();
    // stage 3: av (512 units, 1/block)
    av_unit(bid, Sh, Vt, mask, out, smem);
}

// --------------------------- fallback kernels (r4) --------------------------
__global__ __launch_bounds__(256) void prep_k(
    const float* __restrict__ x,
    const float* __restrict__ Wq, const float* __restrict__ Wk,
    const float* __restrict__ Wv,
    _Float16* Xh, _Float16* WqT, _Float16* WkT, _Float16* WvT)
{
    prep_unit(blockIdx.x, x, Wq, Wk, Wv, Xh, WqT, WkT, WvT);
}

__global__ __launch_bounds__(256, 2) void proj_k(
    const _Float16* Xh,
    const _Float16* WqT, const float* __restrict__ bq,
    const _Float16* WkT, const float* __restrict__ bk,
    const _Float16* WvT, const float* __restrict__ bv,
    _Float16* Qh, _Float16* Kh, _Float16* Vt)
{
    __shared__ __align__(16) _Float16 smem[2 * 16384];
    proj_unit(blockIdx.x, Xh, WqT, bq, WkT, bk, WvT, bv, Qh, Kh, Vt, smem);
}

__global__ __launch_bounds__(256, 2) void scores_k(
    const _Float16* Qh, const _Float16* Kh, _Float16* Sh)
{
    __shared__ __align__(16) _Float16 smem[2 * 16384];
    scores_unit(blockIdx.x, Qh, Kh, Sh, smem);
}

__global__ __launch_bounds__(256, 2) void av_k(
    const _Float16* Sh, const _Float16* Vt,
    const float* __restrict__ mask, float* __restrict__ out)
{
    __shared__ __align__(16) _Float16 smem[2 * 16384];
    av_unit(blockIdx.x, Sh, Vt, mask, out, smem);
}

extern "C" void kernel_launch(void* const* d_in, const int* in_sizes, int n_in,
                              void* d_out, int out_size, void* d_ws, size_t ws_size,
                              hipStream_t stream) {
    const float* x    = (const float*)d_in[0];
    const float* mask = (const float*)d_in[1];
    const float* Wq   = (const float*)d_in[2];
    const float* bq   = (const float*)d_in[3];
    const float* Wk   = (const float*)d_in[4];
    const float* bk   = (const float*)d_in[5];
    const float* Wv   = (const float*)d_in[6];
    const float* bv   = (const float*)d_in[7];
    float* out = (float*)d_out;

    const size_t BSD = (size_t)8 * 2048 * 512;       // 8.4M halves
    _Float16* base = (_Float16*)d_ws;
    _Float16* Qh  = base;
    _Float16* Kh  = Qh + BSD;
    _Float16* Vt  = Kh + BSD;                         // [b][d][s]
    _Float16* WqT = Vt + BSD;
    _Float16* WkT = WqT + 512 * 512;
    _Float16* WvT = WkT + 512 * 512;
    _Float16* Xh  = WvT + 512 * 512;
    _Float16* Sh  = Xh;                               // Xh dead after proj

    void* kargs[] = {
        (void*)&x, (void*)&mask, (void*)&Wq, (void*)&bq, (void*)&Wk,
        (void*)&bk, (void*)&Wv, (void*)&bv, (void*)&out,
        (void*)&Qh, (void*)&Kh, (void*)&Vt,
        (void*)&WqT, (void*)&WkT, (void*)&WvT, (void*)&Xh, (void*)&Sh };
    hipError_t err = hipLaunchCooperativeKernel(
        (const void*)fused_all, dim3(512), dim3(256), kargs, 0, stream);
    if (err != hipSuccess) {
        // fallback: r4 four-kernel pipeline
        prep_k<<<dim3(8192 + 3 * 1024), dim3(256), 0, stream>>>(
            x, Wq, Wk, Wv, Xh, WqT, WkT, WvT);
        proj_k<<<dim3(1536), dim3(256), 0, stream>>>(
            Xh, WqT, bq, WkT, bk, WvT, bv, Qh, Kh, Vt);
        scores_k<<<dim3(2048), dim3(256), 0, stream>>>(Qh, Kh, Sh);
        av_k<<<dim3(512), dim3(256), 0, stream>>>(Sh, Vt, mask, out);
    }
}

// Round 6
// 246.154 us; speedup vs baseline: 1.7748x; 1.7748x over previous
//
#include <hip/hip_runtime.h>
#include <math.h>
#include <stdint.h>

// B=8, S=2048, D=512 single-head self-attention, fp32 in/out, fp16 MFMA inside.
// Round 13 = r4 (210.9us, best) + 4 waves/SIMD:
//   GEMM blocks go 256->512 threads at the SAME 128x128 tile / 64KB dbuf LDS
//   (still 2 blocks/CU) -> 16 waves/CU = 4/SIMD (was 2/SIMD all session).
//   r0-r4 post-mortem: every phase schedule pins at MfmaUtil ~25-30%, VALU
//   low, conflicts 0, HBM <30% = stall-bound; m114/m97 say wave-TLP is what
//   fills barrier+waitcnt stalls (m97's 912TF = 3 waves/SIMD). Per-wave
//   output shrinks 64x64 -> 64x32 (acc[4][2], ~95 VGPR, no spill @128 cap).
// r5 lesson: cooperative fusion = 345us kernel (grid.sync does device-scope
//   L2 writeback/invalidate across 8 XCDs + 512-block spin per boundary,
//   and kills inter-stage L2 reuse). Four graph-captured dispatches win.
//
//  1. prep:        Xh = fp16(x);  W*T = fp16(W^T) for q,k,v
//  2. proj_mfma:   z=0: Qh=(Xh.Wq+bq)/sqrt(512)  z=1: Kh=Xh.Wk+bk
//                  z=2: Vt[b][d][s] = (Xh.Wv + bv)^T  (transposed GEMM)
//  3. scores_mfma: P[b] = fp16(exp(Qh.Kh^T))  UNNORMALIZED (scores ~N(0,1))
//  4. av_mfma:     out[b] = (P.V) * mask[row] / l[row]; l = rowsum(P) via
//                  fdot2 on the A-frags.
//
// Core (8 waves, 2 phases/K-tile, BK=64):
//   wave w: wm=w>>2 (M-half), wn=w&3 (N-quarter); per-wave out 64x32.
//   LDS buffer 32KB: A chunks 0..15 @ c*1KB, B chunks @ 8KB + c*1KB;
//   chunk = 8 rows x 64 halves, 1 async16, XOR-swizzled source, linear dest.
//   Staging per wave: Ah0 = chunk (w&3)+(w>>2)*8 (rows {0-31,64-95} half),
//   Ah1 = +4 (rows {32-63,96-127}), B chunks {2w, 2w+1}.
//   P0: read A-half0(4) + B(4); stage t+1's Ah1 -> other buf | 8 MFMA m0-1
//   P1: read A-half1(4); stage t+2's B0,B1,Ah0 -> this buf; vmcnt(3) | m2-3
//   Ledger: t's chunks = {B,B,Ah0}@P1(t-2) + {Ah1}@P0(t-1); after P1(t-1)
//   issues 3 for t+1, vmcnt(3) leaves exactly those -> t fully landed before
//   P0(t) ds_reads. Regions staged are read-complete one phase earlier
//   (B+Ah0 read in P0; Ah1 read in P1 of previous owner). Race-free.

typedef _Float16 f16x8 __attribute__((ext_vector_type(8)));
typedef _Float16 f16x4 __attribute__((ext_vector_type(4)));
typedef _Float16 f16x2 __attribute__((ext_vector_type(2)));
typedef float f32x4 __attribute__((ext_vector_type(4)));

__device__ __forceinline__ void async16(const _Float16* g, _Float16* l) {
    __builtin_amdgcn_global_load_lds(
        (const __attribute__((address_space(1))) unsigned int*)(uintptr_t)g,
        (__attribute__((address_space(3))) unsigned int*)(unsigned int)(uintptr_t)l,
        16, 0, 0);
}

__device__ __forceinline__ float frag_sum8(f16x8 v, float acc) {
#if __has_builtin(__builtin_amdgcn_fdot2)
    const f16x2 one2 = {(_Float16)1.f, (_Float16)1.f};
    const f16x2* p = (const f16x2*)&v;
    acc = __builtin_amdgcn_fdot2(p[0], one2, acc, false);
    acc = __builtin_amdgcn_fdot2(p[1], one2, acc, false);
    acc = __builtin_amdgcn_fdot2(p[2], one2, acc, false);
    acc = __builtin_amdgcn_fdot2(p[3], one2, acc, false);
#else
#pragma unroll
    for (int j = 0; j < 8; j++) acc += (float)v[j];
#endif
    return acc;
}

#define MFMA16(a, b, c) __builtin_amdgcn_mfma_f32_16x16x32_f16(a, b, c, 0, 0, 0)
#define BAR() __builtin_amdgcn_s_barrier()
#define LGKM0() asm volatile("s_waitcnt lgkmcnt(0)" ::: "memory")

template <int NT, bool WITH_RS>
__device__ __forceinline__ void core8w(
    const _Float16* __restrict__ A, const _Float16* __restrict__ B,
    int ld, int row0, int col0, _Float16* sm, f32x4 acc[4][2], float rs[4])
{
    const int tid = threadIdx.x, lane = tid & 63, wave = tid >> 6;  // 0..7
    const int wm = wave >> 2, wn = wave & 3;
    const int rc = lane >> 3;
    const int swz = ((lane & 7) ^ rc) * 8;
    const int fr = lane & 15, q = lane >> 4, fx = fr & 7;
    const size_t laneoff = (size_t)rc * ld + swz;

    const int ah0c = (wave & 3) + (wave >> 2) * 8;   // {0-3, 8-11}
    const int ah1c = ah0c + 4;                       // {4-7, 12-15}
    const int b0c = 2 * wave, b1c = b0c + 1;         // 0..15
    const _Float16* gAh0 = A + (size_t)(row0 + 8 * ah0c) * ld + laneoff;
    const _Float16* gAh1 = A + (size_t)(row0 + 8 * ah1c) * ld + laneoff;
    const _Float16* gB0  = B + (size_t)(col0 + 8 * b0c) * ld + laneoff;
    const _Float16* gB1  = B + (size_t)(col0 + 8 * b1c) * ld + laneoff;
    const int lAh0 = ah0c * 512, lAh1 = ah1c * 512;
    const int lB0 = 8192 + b0c * 512, lB1 = 8192 + b1c * 512;

    // prologue: t0 full (4/wave), t1: B0,B1,Ah0 (3); t1.Ah1 staged at P0(t=0)
    async16(gAh0, sm + lAh0);
    async16(gAh1, sm + lAh1);
    async16(gB0,  sm + lB0);
    async16(gB1,  sm + lB1);
    async16(gB0 + 64,  sm + 16384 + lB0);
    async16(gB1 + 64,  sm + 16384 + lB1);
    async16(gAh0 + 64, sm + 16384 + lAh0);
    asm volatile("s_waitcnt vmcnt(3)" ::: "memory");
    BAR();

#pragma unroll 2
    for (int t = 0; t < NT; ++t) {
        const _Float16* As = sm + (t & 1) * 16384;
        const _Float16* Bs = As + 8192;
        f16x8 af[2][2], bf[2][2];

        // ---- P0: read A-half0 + B; stage t+1's Ah1 into the other buffer
#pragma unroll
        for (int m = 0; m < 2; m++)
#pragma unroll
            for (int s = 0; s < 2; s++) {
                int ra = wm * 64 + m * 16 + fr;
                af[m][s] = *(const f16x8*)&As[ra * 64 + (((s * 4 + q) ^ fx) * 8)];
            }
#pragma unroll
        for (int n = 0; n < 2; n++)
#pragma unroll
            for (int s = 0; s < 2; s++) {
                int rb = wn * 32 + n * 16 + fr;
                bf[n][s] = *(const f16x8*)&Bs[rb * 64 + (((s * 4 + q) ^ fx) * 8)];
            }
        if (t + 1 < NT)
            async16(gAh1 + (t + 1) * 64, sm + ((t + 1) & 1) * 16384 + lAh1);
        BAR(); LGKM0();
        if (WITH_RS) {
#pragma unroll
            for (int m = 0; m < 2; m++)
#pragma unroll
                for (int s = 0; s < 2; s++) rs[m] = frag_sum8(af[m][s], rs[m]);
        }
        __builtin_amdgcn_s_setprio(1);
#pragma unroll
        for (int s = 0; s < 2; s++)
#pragma unroll
            for (int m = 0; m < 2; m++)
#pragma unroll
                for (int n = 0; n < 2; n++)
                    acc[m][n] = MFMA16(af[m][s], bf[n][s], acc[m][n]);
        __builtin_amdgcn_s_setprio(0);
        BAR();

        // ---- P1: read A-half1; stage t+2's B0,B1,Ah0 into this buffer
#pragma unroll
        for (int m = 0; m < 2; m++)
#pragma unroll
            for (int s = 0; s < 2; s++) {
                int ra = wm * 64 + (2 + m) * 16 + fr;
                af[m][s] = *(const f16x8*)&As[ra * 64 + (((s * 4 + q) ^ fx) * 8)];
            }
        if (t + 2 < NT) {
            _Float16* stg = sm + (t & 1) * 16384;
            const int k2 = (t + 2) * 64;
            async16(gB0 + k2,  stg + lB0);
            async16(gB1 + k2,  stg + lB1);
            async16(gAh0 + k2, stg + lAh0);
        }
        BAR(); LGKM0();
        if (WITH_RS) {
#pragma unroll
            for (int m = 0; m < 2; m++)
#pragma unroll
                for (int s = 0; s < 2; s++) rs[2 + m] = frag_sum8(af[m][s], rs[2 + m]);
        }
        __builtin_amdgcn_s_setprio(1);
#pragma unroll
        for (int s = 0; s < 2; s++)
#pragma unroll
            for (int m = 0; m < 2; m++)
#pragma unroll
                for (int n = 0; n < 2; n++)
                    acc[2 + m][n] = MFMA16(af[m][s], bf[n][s], acc[2 + m][n]);
        __builtin_amdgcn_s_setprio(0);
        if (t + 2 < NT) {
            asm volatile("s_waitcnt vmcnt(3)" ::: "memory");   // t+1 landed
        } else {
            asm volatile("s_waitcnt vmcnt(0)" ::: "memory");   // tail drain
        }
        BAR();
    }
}

// ---------------- 1. prep: x->fp16 and W->fp16 W^T --------------------------
__global__ __launch_bounds__(256) void prep(
    const float* __restrict__ x,
    const float* __restrict__ Wq, const float* __restrict__ Wk,
    const float* __restrict__ Wv,
    _Float16* __restrict__ Xh,
    _Float16* __restrict__ WqT, _Float16* __restrict__ WkT,
    _Float16* __restrict__ WvT)
{
    const int bid = blockIdx.x;
    if (bid < 8192) {                       // convert x: 8.4M elems / 1024
        int i = (bid * 256 + threadIdx.x) * 4;
        float4 v = *(const float4*)(x + i);
        f16x4 h;
        h.x = (_Float16)v.x; h.y = (_Float16)v.y;
        h.z = (_Float16)v.z; h.w = (_Float16)v.w;
        *(f16x4*)&Xh[i] = h;
    } else {                                // transpose W: 3 x 1024 blocks
        int t = bid - 8192;
        int z = t >> 10;
        const float* W = (z == 0) ? Wq : (z == 1) ? Wk : Wv;
        _Float16* Wt   = (z == 0) ? WqT : (z == 1) ? WkT : WvT;
        int idx = (t & 1023) * 256 + threadIdx.x;
        int n = idx >> 9, k = idx & 511;
        Wt[idx] = (_Float16)W[k * 512 + n];
    }
}

// ---------------- 2. projections --------------------------------------------
// grid (x=128, y=4, z=3), 512 thr. z<2: row0=bx*128 (X rows), col0=by*128.
// z=2: row0=by*128 (d), col0=bx*128 (s_global). 4 col-blocks of one row-tile
// have bids differing by 128 (=0 mod 8) -> same XCD -> X rows fetched once.
__global__ __launch_bounds__(512, 4) void proj_mfma(
    const _Float16* __restrict__ Xh,
    const _Float16* __restrict__ WqT, const float* __restrict__ bq,
    const _Float16* __restrict__ WkT, const float* __restrict__ bk,
    const _Float16* __restrict__ WvT, const float* __restrict__ bv,
    _Float16* __restrict__ Qh, _Float16* __restrict__ Kh,
    _Float16* __restrict__ Vt)
{
    __shared__ __align__(16) _Float16 smem[2 * 16384];
    const int z = blockIdx.z;
    f32x4 acc[4][2];
#pragma unroll
    for (int i = 0; i < 4; i++)
#pragma unroll
        for (int j = 0; j < 2; j++) acc[i][j] = (f32x4){0.f, 0.f, 0.f, 0.f};
    float rs_unused[4];

    const int lane = threadIdx.x & 63, wave = threadIdx.x >> 6;
    const int wm = wave >> 2, wn = wave & 3;
    const int er = (lane >> 4) * 4, ec = lane & 15;  // C/D: col=lane&15

    if (z < 2) {
        const _Float16* Wt = (z == 0) ? WqT : WkT;
        const float* bias  = (z == 0) ? bq : bk;
        _Float16* P        = (z == 0) ? Qh : Kh;
        const float sc     = (z == 0) ? 0.04419417382415922f : 1.0f;
        const int row0 = blockIdx.x * 128, col0 = blockIdx.y * 128;
        core8w<8, false>(Xh, Wt, 512, row0, col0, smem, acc, rs_unused);
#pragma unroll
        for (int tm = 0; tm < 4; tm++)
#pragma unroll
            for (int tn = 0; tn < 2; tn++) {
                int col = col0 + wn * 32 + tn * 16 + ec;
                float bb = bias[col];
#pragma unroll
                for (int r = 0; r < 4; r++) {
                    int row = row0 + wm * 64 + tm * 16 + er + r;
                    P[(size_t)row * 512 + col] = (_Float16)((acc[tm][tn][r] + bb) * sc);
                }
            }
    } else {
        // transposed V: out(row=d, col=s_global) = sum_k WvT[d][k] * Xh[s][k]
        const int row0 = blockIdx.y * 128;   // d (M=512)
        const int col0 = blockIdx.x * 128;   // s_global (N=16384)
        core8w<8, false>(WvT, Xh, 512, row0, col0, smem, acc, rs_unused);
#pragma unroll
        for (int tm = 0; tm < 4; tm++)
#pragma unroll
            for (int tn = 0; tn < 2; tn++) {
                int col = col0 + wn * 32 + tn * 16 + ec;   // s_global
                size_t obase = (size_t)(col >> 11) * (512 * 2048) + (col & 2047);
#pragma unroll
                for (int r = 0; r < 4; r++) {
                    int row = row0 + wm * 64 + tm * 16 + er + r;  // d
                    Vt[obase + (size_t)row * 2048] = (_Float16)(acc[tm][tn][r] + bv[row]);
                }
            }
    }
}

// ---------------- 3. scores: P = exp(Q.K^T) (unnormalized) ------------------
// grid 2048: batch = bid&7 (XCD pin: Q[b]+K[b]=4MB=one XCD L2), col fastest.
__global__ __launch_bounds__(512, 4) void scores_mfma(
    const _Float16* __restrict__ Qh, const _Float16* __restrict__ Kh,
    _Float16* __restrict__ Sh)
{
    __shared__ __align__(16) _Float16 smem[2 * 16384];
    const int bid = blockIdx.x;
    const int b   = bid & 7;
    const int rem = bid >> 3;
    const int col0 = (rem & 15) * 128;
    const int row0 = (rem >> 4) * 128;

    const _Float16* A = Qh + (size_t)b * 2048 * 512;
    const _Float16* B = Kh + (size_t)b * 2048 * 512;
    _Float16* S = Sh + (size_t)b * 2048 * 2048;

    f32x4 acc[4][2];
#pragma unroll
    for (int i = 0; i < 4; i++)
#pragma unroll
        for (int j = 0; j < 2; j++) acc[i][j] = (f32x4){0.f, 0.f, 0.f, 0.f};
    float rs_unused[4];

    core8w<8, false>(A, B, 512, row0, col0, smem, acc, rs_unused);

    const int lane = threadIdx.x & 63, wave = threadIdx.x >> 6;
    const int wm = wave >> 2, wn = wave & 3;
    const int er = (lane >> 4) * 4, ec = lane & 15;
#pragma unroll
    for (int tm = 0; tm < 4; tm++)
#pragma unroll
        for (int tn = 0; tn < 2; tn++) {
            int col = col0 + wn * 32 + tn * 16 + ec;
#pragma unroll
            for (int r = 0; r < 4; r++) {
                int row = row0 + wm * 64 + tm * 16 + er + r;
                S[(size_t)row * 2048 + col] = (_Float16)__expf(acc[tm][tn][r]);
            }
        }
}

// ---------------- 4. out = (P.V) * mask / rowsum(P) -------------------------
// grid 512: batch = bid&7 (XCD pin: P[b] streams through one XCD L2,
// V[b]=2MB resident), col fastest -> the 4 col-blocks of one row-group run
// adjacently and share P rows.
__global__ __launch_bounds__(512, 4) void av_mfma(
    const _Float16* __restrict__ Sh, const _Float16* __restrict__ Vt,
    const float* __restrict__ mask, float* __restrict__ out)
{
    __shared__ __align__(16) _Float16 smem[2 * 16384];
    const int bid = blockIdx.x;
    const int b   = bid & 7;
    const int rem = bid >> 3;
    const int col0 = (rem & 3) * 128;
    const int row0 = (rem >> 2) * 128;

    const _Float16* A = Sh + (size_t)b * 2048 * 2048;
    const _Float16* B = Vt + (size_t)b * 512 * 2048;
    float* O = out + (size_t)b * 2048 * 512;
    const float* mk = mask + (size_t)b * 2048;

    f32x4 acc[4][2];
#pragma unroll
    for (int i = 0; i < 4; i++)
#pragma unroll
        for (int j = 0; j < 2; j++) acc[i][j] = (f32x4){0.f, 0.f, 0.f, 0.f};
    float rs[4] = {0.f, 0.f, 0.f, 0.f};

    core8w<32, true>(A, B, 2048, row0, col0, smem, acc, rs);

    const int lane = threadIdx.x & 63, wave = threadIdx.x >> 6;
    const int wm = wave >> 2, wn = wave & 3;
    const int er = (lane >> 4) * 4, ec = lane & 15;

    // rs[tm]: partial rowsum of row (wm*64+tm*16+(lane&15)) over this lane's
    // k-chunks; butterfly over the 4 q-groups -> full rowsum.
#pragma unroll
    for (int tm = 0; tm < 4; tm++) {
        rs[tm] += __shfl_xor(rs[tm], 16, 64);
        rs[tm] += __shfl_xor(rs[tm], 32, 64);
    }
    __syncthreads();                       // all waves out of the GEMM loop
    float* l_s = (float*)smem;             // alias dead staging LDS
    if (wn == 0 && lane < 16) {            // waves 0 (wm=0) and 4 (wm=1)
#pragma unroll
        for (int tm = 0; tm < 4; tm++) l_s[wm * 64 + tm * 16 + lane] = rs[tm];
    }
    __syncthreads();

#pragma unroll
    for (int tm = 0; tm < 4; tm++)
#pragma unroll
        for (int r = 0; r < 4; r++) {
            int lrow = wm * 64 + tm * 16 + er + r;
            int row = row0 + lrow;
            float s = mk[row] / l_s[lrow];
#pragma unroll
            for (int tn = 0; tn < 2; tn++) {
                int col = col0 + wn * 32 + tn * 16 + ec;
                O[(size_t)row * 512 + col] = acc[tm][tn][r] * s;
            }
        }
}

extern "C" void kernel_launch(void* const* d_in, const int* in_sizes, int n_in,
                              void* d_out, int out_size, void* d_ws, size_t ws_size,
                              hipStream_t stream) {
    const float* x    = (const float*)d_in[0];
    const float* mask = (const float*)d_in[1];
    const float* Wq   = (const float*)d_in[2];
    const float* bq   = (const float*)d_in[3];
    const float* Wk   = (const float*)d_in[4];
    const float* bk   = (const float*)d_in[5];
    const float* Wv   = (const float*)d_in[6];
    const float* bv   = (const float*)d_in[7];
    float* out = (float*)d_out;

    const size_t BSD = (size_t)8 * 2048 * 512;       // 8.4M halves
    _Float16* base = (_Float16*)d_ws;
    _Float16* Qh  = base;
    _Float16* Kh  = Qh + BSD;
    _Float16* Vt  = Kh + BSD;                         // [b][d][s]
    _Float16* WqT = Vt + BSD;
    _Float16* WkT = WqT + 512 * 512;
    _Float16* WvT = WkT + 512 * 512;
    _Float16* Xh  = WvT + 512 * 512;
    _Float16* Sh  = Xh;                               // Xh dead after proj

    prep<<<dim3(8192 + 3 * 1024), dim3(256), 0, stream>>>(
        x, Wq, Wk, Wv, Xh, WqT, WkT, WvT);
    proj_mfma<<<dim3(128, 4, 3), dim3(512), 0, stream>>>(
        Xh, WqT, bq, WkT, bk, WvT, bv, Qh, Kh, Vt);
    scores_mfma<<<dim3(2048), dim3(512), 0, stream>>>(Qh, Kh, Sh);
    av_mfma<<<dim3(512), dim3(512), 0, stream>>>(Sh, Vt, mask, out);
}

// Round 7
// 230.874 us; speedup vs baseline: 1.8923x; 1.0662x over previous
//
#include <hip/hip_runtime.h>
#include <math.h>
#include <stdint.h>

// B=8, S=2048, D=512 single-head self-attention, fp32 in/out, fp16 MFMA inside.
// Round 14 = r4 schedule (210.9us best) at 128x64 tiles -> 3 blocks/CU:
//   - core: 128x64 tile, BK=64, 4 waves 2x2 (per-wave 64x32, acc[4][2]),
//     dbuf LDS 48KB (A 16KB + B 8KB per buffer) -> 3 blocks/CU (144/160KB),
//     __launch_bounds__(256,3) (VGPR cap 170).
//   - r6 lesson: intra-block wave-TLP (8-wave, same tile) amplifies LDS reads
//     1.5x and collapses MfmaUtil 30->18%. Block-level co-residency keeps
//     amplification at 2 waves/chunk and adds independent barrier groups --
//     m97's 912TF ran ~3 blocks/CU with 4-wave blocks.
//   - schedule per K-tile (r4-proven): P0: read Ah0(4)+B(4) frags; stage
//     t+1's Ah1 -> other buf; BAR; lgkm0; 8 MFMA. P1: read Ah1(4); stage
//     t+2's Ah0+B -> this buf; BAR; lgkm0; 8 MFMA; vmcnt(4); BAR.
//     Ledger: tile t = {Ah0,B}@P1(t-2) + {Ah1}@P0(t-1); vmcnt(4) after
//     P1(t)'s 4-chunk issue leaves exactly t+2's chunks -> t+1 fully landed.
//     Stage targets are read-complete one barrier earlier (race-free).
// r5 lesson: cooperative fusion = grid.sync L2 writeback across 8 XCDs = 345us.
// Round-7: XCD pinning (batch=bid&7) kept everywhere.
//
//  1. prep:        Xh = fp16(x);  W*T = fp16(W^T) for q,k,v
//  2. proj_mfma:   z=0: Qh=(Xh.Wq+bq)/sqrt(512)  z=1: Kh=Xh.Wk+bk
//                  z=2: Vt[b][d][s] = (Xh.Wv + bv)^T  (transposed GEMM)
//  3. scores_mfma: P[b] = fp16(exp(Qh.Kh^T))  UNNORMALIZED (scores ~N(0,1))
//  4. av_mfma:     out[b] = (P.V) * mask[row] / l[row]; l = rowsum(P) via
//                  fdot2 on the A-frags (P0: m0,m1; P1: m2,m3).

typedef _Float16 f16x8 __attribute__((ext_vector_type(8)));
typedef _Float16 f16x4 __attribute__((ext_vector_type(4)));
typedef _Float16 f16x2 __attribute__((ext_vector_type(2)));
typedef float f32x4 __attribute__((ext_vector_type(4)));

__device__ __forceinline__ void async16(const _Float16* g, _Float16* l) {
    __builtin_amdgcn_global_load_lds(
        (const __attribute__((address_space(1))) unsigned int*)(uintptr_t)g,
        (__attribute__((address_space(3))) unsigned int*)(unsigned int)(uintptr_t)l,
        16, 0, 0);
}

__device__ __forceinline__ float frag_sum8(f16x8 v, float acc) {
#if __has_builtin(__builtin_amdgcn_fdot2)
    const f16x2 one2 = {(_Float16)1.f, (_Float16)1.f};
    const f16x2* p = (const f16x2*)&v;
    acc = __builtin_amdgcn_fdot2(p[0], one2, acc, false);
    acc = __builtin_amdgcn_fdot2(p[1], one2, acc, false);
    acc = __builtin_amdgcn_fdot2(p[2], one2, acc, false);
    acc = __builtin_amdgcn_fdot2(p[3], one2, acc, false);
#else
#pragma unroll
    for (int j = 0; j < 8; j++) acc += (float)v[j];
#endif
    return acc;
}

#define MFMA16(a, b, c) __builtin_amdgcn_mfma_f32_16x16x32_f16(a, b, c, 0, 0, 0)
#define BAR() __builtin_amdgcn_s_barrier()
#define LGKM0() asm volatile("s_waitcnt lgkmcnt(0)" ::: "memory")

// ---------------------------------------------------------------------------
// core: acc[4][2] += A[row0:+128][0:K] . B[col0:+64][0:K]^T, BK=64, 4 waves.
// LDS buffer 24KB: A chunks 0..15 @ c*1KB, B chunks 0..7 @ 16KB + c*1KB;
// chunk = 8 rows x 64 halves, 1 async16 (XOR-swizzled source, linear dest).
// Element [row][k] at buf[row*64 + ((k/8)^(row&7))*8 + k%8].
// Per-wave chunks: Ah0 {w, 8+w} (rows of m-frags 0,1), Ah1 {4+w, 12+w}
// (m-frags 2,3), B {2w, 2w+1}.
// ---------------------------------------------------------------------------
template <int NT, bool WITH_RS>
__device__ __forceinline__ void core64(
    const _Float16* __restrict__ A, const _Float16* __restrict__ B,
    int ld, int row0, int col0, _Float16* sm, f32x4 acc[4][2], float rs[4])
{
    constexpr int BUFH = 12288;                    // halves per buffer (24KB)
    const int tid = threadIdx.x, lane = tid & 63, wave = tid >> 6;  // 0..3
    const int wm = wave >> 1, wn = wave & 1;
    const int rc = lane >> 3;
    const int swz = ((lane & 7) ^ rc) * 8;
    const int fr = lane & 15, q = lane >> 4, fx = fr & 7;
    const size_t laneoff = (size_t)rc * ld + swz;

    const int c00 = wave, c01 = 8 + wave;          // Ah0
    const int c10 = 4 + wave, c11 = 12 + wave;     // Ah1
    const int cb0 = 2 * wave, cb1 = 2 * wave + 1;  // B
    const _Float16* gA00 = A + (size_t)(row0 + 8 * c00) * ld + laneoff;
    const _Float16* gA01 = A + (size_t)(row0 + 8 * c01) * ld + laneoff;
    const _Float16* gA10 = A + (size_t)(row0 + 8 * c10) * ld + laneoff;
    const _Float16* gA11 = A + (size_t)(row0 + 8 * c11) * ld + laneoff;
    const _Float16* gB0  = B + (size_t)(col0 + 8 * cb0) * ld + laneoff;
    const _Float16* gB1  = B + (size_t)(col0 + 8 * cb1) * ld + laneoff;
    const int l00 = c00 * 512, l01 = c01 * 512;
    const int l10 = c10 * 512, l11 = c11 * 512;
    const int lB0 = 8192 + cb0 * 512, lB1 = 8192 + cb1 * 512;

    // prologue: tile0 full (6/wave) -> buf0; tile1 Ah0+B (4/wave) -> buf1;
    // vmcnt(4) = tile0 landed (tile1's 4 stay in flight).
    async16(gA00, sm + l00);  async16(gA01, sm + l01);
    async16(gA10, sm + l10);  async16(gA11, sm + l11);
    async16(gB0,  sm + lB0);  async16(gB1,  sm + lB1);
    async16(gA00 + 64, sm + BUFH + l00);
    async16(gA01 + 64, sm + BUFH + l01);
    async16(gB0 + 64,  sm + BUFH + lB0);
    async16(gB1 + 64,  sm + BUFH + lB1);
    asm volatile("s_waitcnt vmcnt(4)" ::: "memory");
    BAR();

#pragma unroll 2
    for (int t = 0; t < NT; ++t) {
        const _Float16* As = sm + (t & 1) * BUFH;
        const _Float16* Bs = As + 8192;
        f16x8 af[2][2], bf[2][2];

        // ---- P0: read Ah0 + B; stage t+1's Ah1 into the other buffer
#pragma unroll
        for (int m = 0; m < 2; m++)
#pragma unroll
            for (int s = 0; s < 2; s++) {
                int ra = wm * 64 + m * 16 + fr;
                af[m][s] = *(const f16x8*)&As[ra * 64 + (((s * 4 + q) ^ fx) * 8)];
            }
#pragma unroll
        for (int n = 0; n < 2; n++)
#pragma unroll
            for (int s = 0; s < 2; s++) {
                int rb = wn * 32 + n * 16 + fr;
                bf[n][s] = *(const f16x8*)&Bs[rb * 64 + (((s * 4 + q) ^ fx) * 8)];
            }
        if (t + 1 < NT) {
            _Float16* nb = sm + ((t + 1) & 1) * BUFH;
            const int k1 = (t + 1) * 64;
            async16(gA10 + k1, nb + l10);
            async16(gA11 + k1, nb + l11);
        }
        BAR(); LGKM0();
        if (WITH_RS) {
#pragma unroll
            for (int m = 0; m < 2; m++)
#pragma unroll
                for (int s = 0; s < 2; s++) rs[m] = frag_sum8(af[m][s], rs[m]);
        }
        __builtin_amdgcn_s_setprio(1);
#pragma unroll
        for (int s = 0; s < 2; s++)
#pragma unroll
            for (int m = 0; m < 2; m++)
#pragma unroll
                for (int n = 0; n < 2; n++)
                    acc[m][n] = MFMA16(af[m][s], bf[n][s], acc[m][n]);
        __builtin_amdgcn_s_setprio(0);
        BAR();

        // ---- P1: read Ah1; stage t+2's Ah0+B into this buffer; vmcnt(4)
#pragma unroll
        for (int m = 0; m < 2; m++)
#pragma unroll
            for (int s = 0; s < 2; s++) {
                int ra = wm * 64 + (2 + m) * 16 + fr;
                af[m][s] = *(const f16x8*)&As[ra * 64 + (((s * 4 + q) ^ fx) * 8)];
            }
        if (t + 2 < NT) {
            _Float16* stg = sm + (t & 1) * BUFH;
            const int k2 = (t + 2) * 64;
            async16(gA00 + k2, stg + l00);
            async16(gA01 + k2, stg + l01);
            async16(gB0 + k2,  stg + lB0);
            async16(gB1 + k2,  stg + lB1);
        }
        BAR(); LGKM0();
        if (WITH_RS) {
#pragma unroll
            for (int m = 0; m < 2; m++)
#pragma unroll
                for (int s = 0; s < 2; s++) rs[2 + m] = frag_sum8(af[m][s], rs[2 + m]);
        }
        __builtin_amdgcn_s_setprio(1);
#pragma unroll
        for (int s = 0; s < 2; s++)
#pragma unroll
            for (int m = 0; m < 2; m++)
#pragma unroll
                for (int n = 0; n < 2; n++)
                    acc[2 + m][n] = MFMA16(af[m][s], bf[n][s], acc[2 + m][n]);
        __builtin_amdgcn_s_setprio(0);
        if (t + 2 < NT) {
            asm volatile("s_waitcnt vmcnt(4)" ::: "memory");   // t+1 landed
        } else {
            asm volatile("s_waitcnt vmcnt(0)" ::: "memory");   // tail drain
        }
        BAR();
    }
}

// ---------------- 1. prep: x->fp16 and W->fp16 W^T --------------------------
__global__ __launch_bounds__(256) void prep(
    const float* __restrict__ x,
    const float* __restrict__ Wq, const float* __restrict__ Wk,
    const float* __restrict__ Wv,
    _Float16* __restrict__ Xh,
    _Float16* __restrict__ WqT, _Float16* __restrict__ WkT,
    _Float16* __restrict__ WvT)
{
    const int bid = blockIdx.x;
    if (bid < 8192) {                       // convert x: 8.4M elems / 1024
        int i = (bid * 256 + threadIdx.x) * 4;
        float4 v = *(const float4*)(x + i);
        f16x4 h;
        h.x = (_Float16)v.x; h.y = (_Float16)v.y;
        h.z = (_Float16)v.z; h.w = (_Float16)v.w;
        *(f16x4*)&Xh[i] = h;
    } else {                                // transpose W: 3 x 1024 blocks
        int t = bid - 8192;
        int z = t >> 10;
        const float* W = (z == 0) ? Wq : (z == 1) ? Wk : Wv;
        _Float16* Wt   = (z == 0) ? WqT : (z == 1) ? WkT : WvT;
        int idx = (t & 1023) * 256 + threadIdx.x;
        int n = idx >> 9, k = idx & 511;
        Wt[idx] = (_Float16)W[k * 512 + n];
    }
}

// ---------------- 2. projections --------------------------------------------
// grid (x=128, y=8, z=3), 256 thr. z<2: row0=bx*128 (X rows), col0=by*64.
// col-blocks of one row-tile differ by 128 in bid (=0 mod 8) -> same XCD.
// z=2: idx=by*128+bx in [0,1024): row0=(idx>>8)*128 (d), col0=(idx&255)*64 (s).
__global__ __launch_bounds__(256, 3) void proj_mfma(
    const _Float16* __restrict__ Xh,
    const _Float16* __restrict__ WqT, const float* __restrict__ bq,
    const _Float16* __restrict__ WkT, const float* __restrict__ bk,
    const _Float16* __restrict__ WvT, const float* __restrict__ bv,
    _Float16* __restrict__ Qh, _Float16* __restrict__ Kh,
    _Float16* __restrict__ Vt)
{
    __shared__ __align__(16) _Float16 smem[2 * 12288];
    const int z = blockIdx.z;
    f32x4 acc[4][2];
#pragma unroll
    for (int i = 0; i < 4; i++)
#pragma unroll
        for (int j = 0; j < 2; j++) acc[i][j] = (f32x4){0.f, 0.f, 0.f, 0.f};
    float rs_unused[4];

    const int lane = threadIdx.x & 63, wave = threadIdx.x >> 6;
    const int wm = wave >> 1, wn = wave & 1;
    const int er = (lane >> 4) * 4, ec = lane & 15;  // C/D: col=lane&15

    if (z < 2) {
        const _Float16* Wt = (z == 0) ? WqT : WkT;
        const float* bias  = (z == 0) ? bq : bk;
        _Float16* P        = (z == 0) ? Qh : Kh;
        const float sc     = (z == 0) ? 0.04419417382415922f : 1.0f;
        const int row0 = blockIdx.x * 128, col0 = blockIdx.y * 64;
        core64<8, false>(Xh, Wt, 512, row0, col0, smem, acc, rs_unused);
#pragma unroll
        for (int tm = 0; tm < 4; tm++)
#pragma unroll
            for (int tn = 0; tn < 2; tn++) {
                int col = col0 + wn * 32 + tn * 16 + ec;
                float bb = bias[col];
#pragma unroll
                for (int r = 0; r < 4; r++) {
                    int row = row0 + wm * 64 + tm * 16 + er + r;
                    P[(size_t)row * 512 + col] = (_Float16)((acc[tm][tn][r] + bb) * sc);
                }
            }
    } else {
        // transposed V: out(row=d, col=s_global) = sum_k WvT[d][k] * Xh[s][k]
        const int idx = blockIdx.y * 128 + blockIdx.x;
        const int row0 = (idx >> 8) * 128;   // d (M=512)
        const int col0 = (idx & 255) * 64;   // s_global (N=16384)
        core64<8, false>(WvT, Xh, 512, row0, col0, smem, acc, rs_unused);
#pragma unroll
        for (int tm = 0; tm < 4; tm++)
#pragma unroll
            for (int tn = 0; tn < 2; tn++) {
                int col = col0 + wn * 32 + tn * 16 + ec;   // s_global
                size_t obase = (size_t)(col >> 11) * (512 * 2048) + (col & 2047);
#pragma unroll
                for (int r = 0; r < 4; r++) {
                    int row = row0 + wm * 64 + tm * 16 + er + r;  // d
                    Vt[obase + (size_t)row * 2048] = (_Float16)(acc[tm][tn][r] + bv[row]);
                }
            }
    }
}

// ---------------- 3. scores: P = exp(Q.K^T) (unnormalized) ------------------
// grid 4096: batch = bid&7 (XCD pin: Q[b]+K[b]=4MB=one XCD L2); rem=bid>>3:
// col0=(rem&31)*64 (fastest: 32 col-tiles share the row-block's Q in L2),
// row0=(rem>>5)*128.
__global__ __launch_bounds__(256, 3) void scores_mfma(
    const _Float16* __restrict__ Qh, const _Float16* __restrict__ Kh,
    _Float16* __restrict__ Sh)
{
    __shared__ __align__(16) _Float16 smem[2 * 12288];
    const int bid = blockIdx.x;
    const int b   = bid & 7;
    const int rem = bid >> 3;
    const int col0 = (rem & 31) * 64;
    const int row0 = (rem >> 5) * 128;

    const _Float16* A = Qh + (size_t)b * 2048 * 512;
    const _Float16* B = Kh + (size_t)b * 2048 * 512;
    _Float16* S = Sh + (size_t)b * 2048 * 2048;

    f32x4 acc[4][2];
#pragma unroll
    for (int i = 0; i < 4; i++)
#pragma unroll
        for (int j = 0; j < 2; j++) acc[i][j] = (f32x4){0.f, 0.f, 0.f, 0.f};
    float rs_unused[4];

    core64<8, false>(A, B, 512, row0, col0, smem, acc, rs_unused);

    const int lane = threadIdx.x & 63, wave = threadIdx.x >> 6;
    const int wm = wave >> 1, wn = wave & 1;
    const int er = (lane >> 4) * 4, ec = lane & 15;
#pragma unroll
    for (int tm = 0; tm < 4; tm++)
#pragma unroll
        for (int tn = 0; tn < 2; tn++) {
            int col = col0 + wn * 32 + tn * 16 + ec;
#pragma unroll
            for (int r = 0; r < 4; r++) {
                int row = row0 + wm * 64 + tm * 16 + er + r;
                S[(size_t)row * 2048 + col] = (_Float16)__expf(acc[tm][tn][r]);
            }
        }
}

// ---------------- 4. out = (P.V) * mask / rowsum(P) -------------------------
// grid 1024: batch = bid&7 (XCD pin); rem=bid>>3 in [0,128):
// col0=(rem&7)*64, row0=(rem>>3)*128 (col fastest: 8 col-blocks of one
// row-group run adjacently and share P rows in L2).
__global__ __launch_bounds__(256, 3) void av_mfma(
    const _Float16* __restrict__ Sh, const _Float16* __restrict__ Vt,
    const float* __restrict__ mask, float* __restrict__ out)
{
    __shared__ __align__(16) _Float16 smem[2 * 12288];
    const int bid = blockIdx.x;
    const int b   = bid & 7;
    const int rem = bid >> 3;
    const int col0 = (rem & 7) * 64;
    const int row0 = (rem >> 3) * 128;

    const _Float16* A = Sh + (size_t)b * 2048 * 2048;
    const _Float16* B = Vt + (size_t)b * 512 * 2048;
    float* O = out + (size_t)b * 2048 * 512;
    const float* mk = mask + (size_t)b * 2048;

    f32x4 acc[4][2];
#pragma unroll
    for (int i = 0; i < 4; i++)
#pragma unroll
        for (int j = 0; j < 2; j++) acc[i][j] = (f32x4){0.f, 0.f, 0.f, 0.f};
    float rs[4] = {0.f, 0.f, 0.f, 0.f};

    core64<32, true>(A, B, 2048, row0, col0, smem, acc, rs);

    const int lane = threadIdx.x & 63, wave = threadIdx.x >> 6;
    const int wm = wave >> 1, wn = wave & 1;
    const int er = (lane >> 4) * 4, ec = lane & 15;

    // rs[tm]: partial rowsum of row (wm*64+tm*16+(lane&15)) over this lane's
    // k-chunks; butterfly over the 4 q-groups -> full rowsum.
#pragma unroll
    for (int tm = 0; tm < 4; tm++) {
        rs[tm] += __shfl_xor(rs[tm], 16, 64);
        rs[tm] += __shfl_xor(rs[tm], 32, 64);
    }
    __syncthreads();                       // all waves out of the GEMM loop
    float* l_s = (float*)smem;             // alias dead staging LDS
    if (wn == 0 && lane < 16) {            // waves 0 (wm=0), 2 (wm=1)
#pragma unroll
        for (int tm = 0; tm < 4; tm++) l_s[wm * 64 + tm * 16 + lane] = rs[tm];
    }
    __syncthreads();

#pragma unroll
    for (int tm = 0; tm < 4; tm++)
#pragma unroll
        for (int r = 0; r < 4; r++) {
            int lrow = wm * 64 + tm * 16 + er + r;
            int row = row0 + lrow;
            float s = mk[row] / l_s[lrow];
#pragma unroll
            for (int tn = 0; tn < 2; tn++) {
                int col = col0 + wn * 32 + tn * 16 + ec;
                O[(size_t)row * 512 + col] = acc[tm][tn][r] * s;
            }
        }
}

extern "C" void kernel_launch(void* const* d_in, const int* in_sizes, int n_in,
                              void* d_out, int out_size, void* d_ws, size_t ws_size,
                              hipStream_t stream) {
    const float* x    = (const float*)d_in[0];
    const float* mask = (const float*)d_in[1];
    const float* Wq   = (const float*)d_in[2];
    const float* bq   = (const float*)d_in[3];
    const float* Wk   = (const float*)d_in[4];
    const float* bk   = (const float*)d_in[5];
    const float* Wv   = (const float*)d_in[6];
    const float* bv   = (const float*)d_in[7];
    float* out = (float*)d_out;

    const size_t BSD = (size_t)8 * 2048 * 512;       // 8.4M halves
    _Float16* base = (_Float16*)d_ws;
    _Float16* Qh  = base;
    _Float16* Kh  = Qh + BSD;
    _Float16* Vt  = Kh + BSD;                         // [b][d][s]
    _Float16* WqT = Vt + BSD;
    _Float16* WkT = WqT + 512 * 512;
    _Float16* WvT = WkT + 512 * 512;
    _Float16* Xh  = WvT + 512 * 512;
    _Float16* Sh  = Xh;                               // Xh dead after proj

    prep<<<dim3(8192 + 3 * 1024), dim3(256), 0, stream>>>(
        x, Wq, Wk, Wv, Xh, WqT, WkT, WvT);
    proj_mfma<<<dim3(128, 8, 3), dim3(256), 0, stream>>>(
        Xh, WqT, bq, WkT, bk, WvT, bv, Qh, Kh, Vt);
    scores_mfma<<<dim3(4096), dim3(256), 0, stream>>>(Qh, Kh, Sh);
    av_mfma<<<dim3(1024), dim3(256), 0, stream>>>(Sh, Vt, mask, out);
}

// Round 8
// 224.255 us; speedup vs baseline: 1.9482x; 1.0295x over previous
//
#include <hip/hip_runtime.h>
#include <math.h>
#include <stdint.h>

// B=8, S=2048, D=512 single-head self-attention, fp32 in/out, fp16 MFMA inside.
// Round 15 = r4 (210.9us, session best) with the GEMM core moved from
// 16x16x32 to 32x32x16 MFMA:
//   - identical tiles (128x128, BK=64), identical grids, identical staging
//     chunks / XOR swizzle / vmcnt(6) ledger / 2-phase barrier schedule,
//     identical 64KB dbuf LDS at 2 blocks/CU.
//   - per wave per K-tile: same 16 ds_read_b128 (256B/lane) but 8 MFMA of
//     32x32x16 (32768 FLOP each) instead of 16 of 16x16x32 -> half the issue
//     slots, and the 32x32 pipe's measured ceiling is 2495 vs 2075 TF (+20%).
//   - C/D layout (verified m74/m101): col=lane&31, row=(reg&3)+8*(reg>>2)+
//     4*(lane>>5), reg in [0,16). A-frag: lane holds row lane&31, k-half
//     (lane>>5)*8 -> av rowsum needs only the xor-32 butterfly.
// r7 lesson: 3 blocks/CU via 128x64 tiles REGRESSED (FETCH +18%, MfmaUtil
//   26%): read:MFMA ratio per phase dominates, not co-residency.
// r6 lesson: 8-wave same-tile TLP amplifies LDS reads, MfmaUtil 18%.
// r5 lesson: grid.sync fusion = 345us (XCD L2 writeback per boundary).
//
//  1. prep:        Xh = fp16(x);  W*T = fp16(W^T) for q,k,v
//  2. proj_mfma:   z=0: Qh=(Xh.Wq+bq)/sqrt(512)  z=1: Kh=Xh.Wk+bk
//                  z=2: Vt[b][d][s] = (Xh.Wv + bv)^T  (transposed GEMM)
//  3. scores_mfma: P[b] = fp16(exp(Qh.Kh^T))  UNNORMALIZED (scores ~N(0,1))
//  4. av_mfma:     out[b] = (P.V) * mask[row] / l[row]; l = rowsum(P) via
//                  fdot2 on the A-frags (all A read in P0).

typedef _Float16 f16x8 __attribute__((ext_vector_type(8)));
typedef _Float16 f16x4 __attribute__((ext_vector_type(4)));
typedef _Float16 f16x2 __attribute__((ext_vector_type(2)));
typedef float f32x4 __attribute__((ext_vector_type(4)));
typedef float f32x16 __attribute__((ext_vector_type(16)));

__device__ __forceinline__ void async16(const _Float16* g, _Float16* l) {
    __builtin_amdgcn_global_load_lds(
        (const __attribute__((address_space(1))) unsigned int*)(uintptr_t)g,
        (__attribute__((address_space(3))) unsigned int*)(unsigned int)(uintptr_t)l,
        16, 0, 0);
}

__device__ __forceinline__ float frag_sum8(f16x8 v, float acc) {
#if __has_builtin(__builtin_amdgcn_fdot2)
    const f16x2 one2 = {(_Float16)1.f, (_Float16)1.f};
    const f16x2* p = (const f16x2*)&v;
    acc = __builtin_amdgcn_fdot2(p[0], one2, acc, false);
    acc = __builtin_amdgcn_fdot2(p[1], one2, acc, false);
    acc = __builtin_amdgcn_fdot2(p[2], one2, acc, false);
    acc = __builtin_amdgcn_fdot2(p[3], one2, acc, false);
#else
#pragma unroll
    for (int j = 0; j < 8; j++) acc += (float)v[j];
#endif
    return acc;
}

#define MFMA32(a, b, c) __builtin_amdgcn_mfma_f32_32x32x16_f16(a, b, c, 0, 0, 0)
#define BAR() __builtin_amdgcn_s_barrier()
#define LGKM0() asm volatile("s_waitcnt lgkmcnt(0)" ::: "memory")

// ---------------------------------------------------------------------------
// core: acc[2][2](32x32 frags) += A[row0:+128][0:K].B[col0:+128][0:K]^T,
// BK=64, 4 waves 2x2 (per-wave 64x64). LDS buffer 32KB: A chunks 0..15 at
// c*1KB, B chunks 0..15 at 8KB + c*1KB; chunk = 8 rows x 64 halves, staged by
// one async16 (XOR-swizzled global source, linear LDS dest). Element
// [row][k] at buf[row*64 + ((k/8)^(row&7))*8 + k%8].
// Frag reads (32x32x16): lane -> row (lane&31), k = s*16 + (lane>>5)*8.
//  P0: read A all (8) + B n-frag0 (4); stage t+1's B-late -> other buf;
//      BAR; lgkm0; [rowsum]; 8 MFMA (nf=0); BAR.
//  P1: read B n-frag1 (4); stage t+2's A+B-early -> this buf; vmcnt(6);
//      BAR; lgkm0; 8 MFMA (nf=1); BAR.
//  Ledger: tile t = {A,Bearly}@P1(t-2) + {Blate}@P0(t-1); vmcnt(6) after
//  P1(t)'s 6-chunk issue waits until t+1's 8 have landed. Stage targets are
//  read-complete one barrier earlier (race-free, unchanged from r4).
// ---------------------------------------------------------------------------
template <int NT, bool WITH_RS>
__device__ __forceinline__ void core128sq(
    const _Float16* __restrict__ A, const _Float16* __restrict__ B,
    int ld, int row0, int col0, _Float16* sm, f32x16 acc[2][2], float rs[2])
{
    const int tid = threadIdx.x, lane = tid & 63, wave = tid >> 6;
    const int wm = wave >> 1, wn = wave & 1;
    const int rc = lane >> 3;
    const int swz = ((lane & 7) ^ rc) * 8;
    const int fr32 = lane & 31, q2 = lane >> 5, fx = fr32 & 7;
    const size_t laneoff = (size_t)rc * ld + swz;

    const _Float16* gA[4]; int lA[4];
#pragma unroll
    for (int i = 0; i < 4; i++) {
        int c = wave * 4 + i;                        // A chunks 0..15
        gA[i] = A + (size_t)(row0 + 8 * c) * ld + laneoff;
        lA[i] = c * 512;
    }
    const _Float16* gBe[2]; const _Float16* gBl[2]; int lBe[2], lBl[2];
#pragma unroll
    for (int i = 0; i < 2; i++) {
        int idx = wave * 2 + i;                      // 0..7
        int je = (idx & 3) + (idx >> 2) * 8;         // early {0-3,8-11}: cols 0-31,64-95
        int jl = je + 4;                             // late  {4-7,12-15}: cols 32-63,96-127
        gBe[i] = B + (size_t)(col0 + 8 * je) * ld + laneoff;
        gBl[i] = B + (size_t)(col0 + 8 * jl) * ld + laneoff;
        lBe[i] = 8192 + je * 512;
        lBl[i] = 8192 + jl * 512;
    }

    // prologue: tile0 full (8/wave), tile1 A+Bearly (6/wave); vmcnt(6)=t0 done
#pragma unroll
    for (int i = 0; i < 4; i++) async16(gA[i], sm + lA[i]);
#pragma unroll
    for (int i = 0; i < 2; i++) async16(gBe[i], sm + lBe[i]);
#pragma unroll
    for (int i = 0; i < 2; i++) async16(gBl[i], sm + lBl[i]);
#pragma unroll
    for (int i = 0; i < 4; i++) async16(gA[i] + 64, sm + 16384 + lA[i]);
#pragma unroll
    for (int i = 0; i < 2; i++) async16(gBe[i] + 64, sm + 16384 + lBe[i]);
    asm volatile("s_waitcnt vmcnt(6)" ::: "memory");
    BAR();

#pragma unroll 2
    for (int t = 0; t < NT; ++t) {
        const _Float16* As = sm + (t & 1) * 16384;
        const _Float16* Bs = As + 8192;
        f16x8 af[2][4], bf[4];

        // ---- P0: read A(all) + B nf=0; stage t+1's B-late into other buffer
#pragma unroll
        for (int m = 0; m < 2; m++)
#pragma unroll
            for (int s = 0; s < 4; s++) {
                int ra = wm * 64 + m * 32 + fr32;
                af[m][s] = *(const f16x8*)&As[ra * 64 + (((2 * s + q2) ^ fx) * 8)];
            }
#pragma unroll
        for (int s = 0; s < 4; s++) {
            int rb = wn * 64 + fr32;
            bf[s] = *(const f16x8*)&Bs[rb * 64 + (((2 * s + q2) ^ fx) * 8)];
        }
        if (t + 1 < NT) {
            _Float16* nb = sm + ((t + 1) & 1) * 16384;
#pragma unroll
            for (int i = 0; i < 2; i++)
                async16(gBl[i] + (t + 1) * 64, nb + lBl[i]);
        }
        BAR(); LGKM0();
        if (WITH_RS) {
#pragma unroll
            for (int m = 0; m < 2; m++)
#pragma unroll
                for (int s = 0; s < 4; s++) rs[m] = frag_sum8(af[m][s], rs[m]);
        }
        __builtin_amdgcn_s_setprio(1);
#pragma unroll
        for (int s = 0; s < 4; s++)
#pragma unroll
            for (int m = 0; m < 2; m++)
                acc[m][0] = MFMA32(af[m][s], bf[s], acc[m][0]);
        __builtin_amdgcn_s_setprio(0);
        BAR();

        // ---- P1: read B nf=1; stage t+2's A+B-early into this buffer
#pragma unroll
        for (int s = 0; s < 4; s++) {
            int rb = wn * 64 + 32 + fr32;
            bf[s] = *(const f16x8*)&Bs[rb * 64 + (((2 * s + q2) ^ fx) * 8)];
        }
        if (t + 2 < NT) {
            _Float16* stg = sm + (t & 1) * 16384;
            const int k2 = (t + 2) * 64;
#pragma unroll
            for (int i = 0; i < 4; i++) async16(gA[i] + k2, stg + lA[i]);
#pragma unroll
            for (int i = 0; i < 2; i++) async16(gBe[i] + k2, stg + lBe[i]);
            asm volatile("s_waitcnt vmcnt(6)" ::: "memory");   // t+1 landed
        } else {
            asm volatile("s_waitcnt vmcnt(0)" ::: "memory");   // tail drain
        }
        BAR(); LGKM0();
        __builtin_amdgcn_s_setprio(1);
#pragma unroll
        for (int s = 0; s < 4; s++)
#pragma unroll
            for (int m = 0; m < 2; m++)
                acc[m][1] = MFMA32(af[m][s], bf[s], acc[m][1]);
        __builtin_amdgcn_s_setprio(0);
        BAR();
    }
}

// ---------------- 1. prep: x->fp16 and W->fp16 W^T --------------------------
__global__ __launch_bounds__(256) void prep(
    const float* __restrict__ x,
    const float* __restrict__ Wq, const float* __restrict__ Wk,
    const float* __restrict__ Wv,
    _Float16* __restrict__ Xh,
    _Float16* __restrict__ WqT, _Float16* __restrict__ WkT,
    _Float16* __restrict__ WvT)
{
    const int bid = blockIdx.x;
    if (bid < 8192) {                       // convert x: 8.4M elems / 1024
        int i = (bid * 256 + threadIdx.x) * 4;
        float4 v = *(const float4*)(x + i);
        f16x4 h;
        h.x = (_Float16)v.x; h.y = (_Float16)v.y;
        h.z = (_Float16)v.z; h.w = (_Float16)v.w;
        *(f16x4*)&Xh[i] = h;
    } else {                                // transpose W: 3 x 1024 blocks
        int t = bid - 8192;
        int z = t >> 10;
        const float* W = (z == 0) ? Wq : (z == 1) ? Wk : Wv;
        _Float16* Wt   = (z == 0) ? WqT : (z == 1) ? WkT : WvT;
        int idx = (t & 1023) * 256 + threadIdx.x;
        int n = idx >> 9, k = idx & 511;
        Wt[idx] = (_Float16)W[k * 512 + n];
    }
}

// ---------------- 2. projections --------------------------------------------
// grid (x=128, y=4, z=3), 256 thr. z<2: row0=bx*128 (X rows), col0=by*128.
// z=2: row0=by*128 (d), col0=bx*128 (s_global). 4 col-blocks of one row-tile
// have bids differing by 128 (=0 mod 8) -> same XCD -> X rows fetched once.
__global__ __launch_bounds__(256, 2) void proj_mfma(
    const _Float16* __restrict__ Xh,
    const _Float16* __restrict__ WqT, const float* __restrict__ bq,
    const _Float16* __restrict__ WkT, const float* __restrict__ bk,
    const _Float16* __restrict__ WvT, const float* __restrict__ bv,
    _Float16* __restrict__ Qh, _Float16* __restrict__ Kh,
    _Float16* __restrict__ Vt)
{
    __shared__ __align__(16) _Float16 smem[2 * 16384];
    const int z = blockIdx.z;
    f32x16 acc[2][2] = {};
    float rs_unused[2];

    const int lane = threadIdx.x & 63, wave = threadIdx.x >> 6;
    const int wm = wave >> 1, wn = wave & 1;
    const int fr32 = lane & 31, q2 = lane >> 5;

    if (z < 2) {
        const _Float16* Wt = (z == 0) ? WqT : WkT;
        const float* bias  = (z == 0) ? bq : bk;
        _Float16* P        = (z == 0) ? Qh : Kh;
        const float sc     = (z == 0) ? 0.04419417382415922f : 1.0f;
        const int row0 = blockIdx.x * 128, col0 = blockIdx.y * 128;
        core128sq<8, false>(Xh, Wt, 512, row0, col0, smem, acc, rs_unused);
#pragma unroll
        for (int mf = 0; mf < 2; mf++)
#pragma unroll
            for (int nf = 0; nf < 2; nf++) {
                int col = col0 + wn * 64 + nf * 32 + fr32;
                float bb = bias[col];
#pragma unroll
                for (int reg = 0; reg < 16; reg++) {
                    int row = row0 + wm * 64 + mf * 32 +
                              (reg & 3) + 8 * (reg >> 2) + 4 * q2;
                    P[(size_t)row * 512 + col] = (_Float16)((acc[mf][nf][reg] + bb) * sc);
                }
            }
    } else {
        // transposed V: out(row=d, col=s_global) = sum_k WvT[d][k] * Xh[s][k]
        const int row0 = blockIdx.y * 128;   // d (M=512)
        const int col0 = blockIdx.x * 128;   // s_global (N=16384)
        core128sq<8, false>(WvT, Xh, 512, row0, col0, smem, acc, rs_unused);
#pragma unroll
        for (int mf = 0; mf < 2; mf++)
#pragma unroll
            for (int nf = 0; nf < 2; nf++) {
                int col = col0 + wn * 64 + nf * 32 + fr32;   // s_global
                size_t obase = (size_t)(col >> 11) * (512 * 2048) + (col & 2047);
#pragma unroll
                for (int reg = 0; reg < 16; reg++) {
                    int row = row0 + wm * 64 + mf * 32 +
                              (reg & 3) + 8 * (reg >> 2) + 4 * q2;  // d
                    Vt[obase + (size_t)row * 2048] = (_Float16)(acc[mf][nf][reg] + bv[row]);
                }
            }
    }
}

// ---------------- 3. scores: P = exp(Q.K^T) (unnormalized) ------------------
// grid 2048: batch = bid&7 (XCD pin: Q[b]+K[b]=4MB=one XCD L2), col fastest.
__global__ __launch_bounds__(256, 2) void scores_mfma(
    const _Float16* __restrict__ Qh, const _Float16* __restrict__ Kh,
    _Float16* __restrict__ Sh)
{
    __shared__ __align__(16) _Float16 smem[2 * 16384];
    const int bid = blockIdx.x;
    const int b   = bid & 7;
    const int rem = bid >> 3;
    const int col0 = (rem & 15) * 128;
    const int row0 = (rem >> 4) * 128;

    const _Float16* A = Qh + (size_t)b * 2048 * 512;
    const _Float16* B = Kh + (size_t)b * 2048 * 512;
    _Float16* S = Sh + (size_t)b * 2048 * 2048;

    f32x16 acc[2][2] = {};
    float rs_unused[2];

    core128sq<8, false>(A, B, 512, row0, col0, smem, acc, rs_unused);

    const int lane = threadIdx.x & 63, wave = threadIdx.x >> 6;
    const int wm = wave >> 1, wn = wave & 1;
    const int fr32 = lane & 31, q2 = lane >> 5;
#pragma unroll
    for (int mf = 0; mf < 2; mf++)
#pragma unroll
        for (int nf = 0; nf < 2; nf++) {
            int col = col0 + wn * 64 + nf * 32 + fr32;
#pragma unroll
            for (int reg = 0; reg < 16; reg++) {
                int row = row0 + wm * 64 + mf * 32 +
                          (reg & 3) + 8 * (reg >> 2) + 4 * q2;
                S[(size_t)row * 2048 + col] = (_Float16)__expf(acc[mf][nf][reg]);
            }
        }
}

// ---------------- 4. out = (P.V) * mask / rowsum(P) -------------------------
// grid 512: batch = bid&7 (XCD pin: P[b] streams through one XCD L2,
// V[b]=2MB resident), col fastest -> the 4 col-blocks of one row-group run
// adjacently and share P rows.
__global__ __launch_bounds__(256, 2) void av_mfma(
    const _Float16* __restrict__ Sh, const _Float16* __restrict__ Vt,
    const float* __restrict__ mask, float* __restrict__ out)
{
    __shared__ __align__(16) _Float16 smem[2 * 16384];
    const int bid = blockIdx.x;
    const int b   = bid & 7;
    const int rem = bid >> 3;
    const int col0 = (rem & 3) * 128;
    const int row0 = (rem >> 2) * 128;

    const _Float16* A = Sh + (size_t)b * 2048 * 2048;
    const _Float16* B = Vt + (size_t)b * 512 * 2048;
    float* O = out + (size_t)b * 2048 * 512;
    const float* mk = mask + (size_t)b * 2048;

    f32x16 acc[2][2] = {};
    float rs[2] = {0.f, 0.f};

    core128sq<32, true>(A, B, 2048, row0, col0, smem, acc, rs);

    const int lane = threadIdx.x & 63, wave = threadIdx.x >> 6;
    const int wm = wave >> 1, wn = wave & 1;
    const int fr32 = lane & 31, q2 = lane >> 5;

    // rs[mf]: partial rowsum of row (wm*64+mf*32+fr32) over this lane's
    // k-halves (bit3 of k == q2); xor-32 butterfly completes it.
#pragma unroll
    for (int mf = 0; mf < 2; mf++) rs[mf] += __shfl_xor(rs[mf], 32, 64);
    __syncthreads();                       // all waves out of the GEMM loop
    float* l_s = (float*)smem;             // alias dead staging LDS
    if (wn == 0 && lane < 32) {            // waves 0 (wm=0), 2 (wm=1)
#pragma unroll
        for (int mf = 0; mf < 2; mf++) l_s[wm * 64 + mf * 32 + lane] = rs[mf];
    }
    __syncthreads();

#pragma unroll
    for (int mf = 0; mf < 2; mf++)
#pragma unroll
        for (int nf = 0; nf < 2; nf++) {
            int col = col0 + wn * 64 + nf * 32 + fr32;
#pragma unroll
            for (int reg = 0; reg < 16; reg++) {
                int lrow = wm * 64 + mf * 32 + (reg & 3) + 8 * (reg >> 2) + 4 * q2;
                int row = row0 + lrow;
                float s = mk[row] / l_s[lrow];
                O[(size_t)row * 512 + col] = acc[mf][nf][reg] * s;
            }
        }
}

extern "C" void kernel_launch(void* const* d_in, const int* in_sizes, int n_in,
                              void* d_out, int out_size, void* d_ws, size_t ws_size,
                              hipStream_t stream) {
    const float* x    = (const float*)d_in[0];
    const float* mask = (const float*)d_in[1];
    const float* Wq   = (const float*)d_in[2];
    const float* bq   = (const float*)d_in[3];
    const float* Wk   = (const float*)d_in[4];
    const float* bk   = (const float*)d_in[5];
    const float* Wv   = (const float*)d_in[6];
    const float* bv   = (const float*)d_in[7];
    float* out = (float*)d_out;

    const size_t BSD = (size_t)8 * 2048 * 512;       // 8.4M halves
    _Float16* base = (_Float16*)d_ws;
    _Float16* Qh  = base;
    _Float16* Kh  = Qh + BSD;
    _Float16* Vt  = Kh + BSD;                         // [b][d][s]
    _Float16* WqT = Vt + BSD;
    _Float16* WkT = WqT + 512 * 512;
    _Float16* WvT = WkT + 512 * 512;
    _Float16* Xh  = WvT + 512 * 512;
    _Float16* Sh  = Xh;                               // Xh dead after proj

    prep<<<dim3(8192 + 3 * 1024), dim3(256), 0, stream>>>(
        x, Wq, Wk, Wv, Xh, WqT, WkT, WvT);
    proj_mfma<<<dim3(128, 4, 3), dim3(256), 0, stream>>>(
        Xh, WqT, bq, WkT, bk, WvT, bv, Qh, Kh, Vt);
    scores_mfma<<<dim3(2048), dim3(256), 0, stream>>>(Qh, Kh, Sh);
    av_mfma<<<dim3(512), dim3(256), 0, stream>>>(Sh, Vt, mask, out);
}

// Round 9
// 214.573 us; speedup vs baseline: 2.0361x; 1.0451x over previous
//
#include <hip/hip_runtime.h>
#include <math.h>
#include <stdint.h>

// B=8, S=2048, D=512 single-head self-attention, fp32 in/out, fp16 MFMA inside.
// Round 16 = r8 (32x32x16 core) + repaired 3-term XOR swizzle:
//   r8 counter: SQ_LDS_BANK_CONFLICT 0 -> 4.19M, av 44->52us. Cause: with
//   fr32=lane&31, lanes l and l+16 read the SAME k-slot at rows 16 apart;
//   row stride = 128B = exact bank wrap -> same banks. The 2-term swizzle
//   slot=(k/8)^(row&7) cannot separate rows 8/16/24 apart.
//   Fix: slot = (k/8) ^ (row&7) ^ ((row>>3)&3).
//     stage: chunk c, lane l sources global slot (l&7)^(l>>3)^(c&3), writes
//            linearly (both-sides-or-neither, m104/m231 rule respected).
//     read:  kc = ((2s+q2) ^ (lane&7) ^ ((lane>>3)&3)) * 8
//            (row terms: (ra&7)=lane&7, ((ra>>3)&3)=(lane>>3)&3 since the
//             wm/m/nf offsets are multiples of 32).
//   Now any co-issued lane group {l, l+8k} has distinct slots -> 0 conflicts.
// Everything else identical to r8/r4: 128x128 tile, BK=64, 4 waves 2x2,
// 64KB dbuf LDS (2 blocks/CU), 2-phase m201-style schedule, vmcnt(6) ledger,
// 8 MFMA 32x32x16 per tile (2495 TF pipe ceiling vs 2075 for 16x16).
// r7 lesson: 128x64 tiles/3 blocks/CU regressed (FETCH +18%).
// r6 lesson: 8-wave same-tile TLP regressed (LDS amplification).
// r5 lesson: grid.sync fusion = 345us.
//
//  1. prep:        Xh = fp16(x);  W*T = fp16(W^T) for q,k,v
//  2. proj_mfma:   z=0: Qh=(Xh.Wq+bq)/sqrt(512)  z=1: Kh=Xh.Wk+bk
//                  z=2: Vt[b][d][s] = (Xh.Wv + bv)^T  (transposed GEMM)
//  3. scores_mfma: P[b] = fp16(exp(Qh.Kh^T))  UNNORMALIZED (scores ~N(0,1))
//  4. av_mfma:     out[b] = (P.V) * mask[row] / l[row]; l = rowsum(P) via
//                  fdot2 on the A-frags (all A read in P0).

typedef _Float16 f16x8 __attribute__((ext_vector_type(8)));
typedef _Float16 f16x4 __attribute__((ext_vector_type(4)));
typedef _Float16 f16x2 __attribute__((ext_vector_type(2)));
typedef float f32x4 __attribute__((ext_vector_type(4)));
typedef float f32x16 __attribute__((ext_vector_type(16)));

__device__ __forceinline__ void async16(const _Float16* g, _Float16* l) {
    __builtin_amdgcn_global_load_lds(
        (const __attribute__((address_space(1))) unsigned int*)(uintptr_t)g,
        (__attribute__((address_space(3))) unsigned int*)(unsigned int)(uintptr_t)l,
        16, 0, 0);
}

__device__ __forceinline__ float frag_sum8(f16x8 v, float acc) {
#if __has_builtin(__builtin_amdgcn_fdot2)
    const f16x2 one2 = {(_Float16)1.f, (_Float16)1.f};
    const f16x2* p = (const f16x2*)&v;
    acc = __builtin_amdgcn_fdot2(p[0], one2, acc, false);
    acc = __builtin_amdgcn_fdot2(p[1], one2, acc, false);
    acc = __builtin_amdgcn_fdot2(p[2], one2, acc, false);
    acc = __builtin_amdgcn_fdot2(p[3], one2, acc, false);
#else
#pragma unroll
    for (int j = 0; j < 8; j++) acc += (float)v[j];
#endif
    return acc;
}

#define MFMA32(a, b, c) __builtin_amdgcn_mfma_f32_32x32x16_f16(a, b, c, 0, 0, 0)
#define BAR() __builtin_amdgcn_s_barrier()
#define LGKM0() asm volatile("s_waitcnt lgkmcnt(0)" ::: "memory")

// ---------------------------------------------------------------------------
// core: acc[2][2](32x32 frags) += A[row0:+128][0:K].B[col0:+128][0:K]^T,
// BK=64, 4 waves 2x2 (per-wave 64x64). LDS buffer 32KB: A chunks 0..15 at
// c*1KB, B chunks 0..15 at 8KB + c*1KB; chunk = 8 rows x 64 halves, staged by
// one async16 (pre-swizzled global source, linear LDS dest).
// Swizzle (3-term): element [row][k] at buf[row*64 + ((k/8)^(row&7)^((row>>3)&3))*8 + k%8].
// Frag reads (32x32x16): lane -> row (lane&31), k = s*16 + (lane>>5)*8.
//  P0: read A all (8) + B nf=0 (4); stage t+1's B-late -> other buf;
//      BAR; lgkm0; [rowsum]; 8 MFMA (nf=0); BAR.
//  P1: read B nf=1 (4); stage t+2's A+B-early -> this buf; vmcnt(6);
//      BAR; lgkm0; 8 MFMA (nf=1); BAR.
//  Ledger: tile t = {A,Bearly}@P1(t-2) + {Blate}@P0(t-1); vmcnt(6) after
//  P1(t)'s 6-chunk issue waits until t+1's 8 have landed. Stage targets are
//  read-complete one barrier earlier (race-free, unchanged from r4).
// ---------------------------------------------------------------------------
template <int NT, bool WITH_RS>
__device__ __forceinline__ void core128sq(
    const _Float16* __restrict__ A, const _Float16* __restrict__ B,
    int ld, int row0, int col0, _Float16* sm, f32x16 acc[2][2], float rs[2])
{
    const int tid = threadIdx.x, lane = tid & 63, wave = tid >> 6;
    const int wm = wave >> 1, wn = wave & 1;
    const int rc = lane >> 3;                      // row within 8-row chunk
    const int l7 = lane & 7;
    const int fr32 = lane & 31, q2 = lane >> 5;
    const int fx = fr32 & 7;                       // = l7
    const int rq = (lane >> 3) & 3;                // ((row>>3)&3) for frag reads

    const _Float16* gA[4]; int lA[4];
#pragma unroll
    for (int i = 0; i < 4; i++) {
        int c = wave * 4 + i;                      // A chunks 0..15
        int swz = ((l7 ^ rc ^ (c & 3)) * 8);
        gA[i] = A + (size_t)(row0 + 8 * c + rc) * ld + swz;
        lA[i] = c * 512;
    }
    const _Float16* gBe[2]; const _Float16* gBl[2]; int lBe[2], lBl[2];
#pragma unroll
    for (int i = 0; i < 2; i++) {
        int idx = wave * 2 + i;                    // 0..7
        int je = (idx & 3) + (idx >> 2) * 8;       // early {0-3,8-11}: cols 0-31,64-95
        int jl = je + 4;                           // late  {4-7,12-15}: cols 32-63,96-127
        int swze = ((l7 ^ rc ^ (je & 3)) * 8);
        int swzl = ((l7 ^ rc ^ (jl & 3)) * 8);
        gBe[i] = B + (size_t)(col0 + 8 * je + rc) * ld + swze;
        gBl[i] = B + (size_t)(col0 + 8 * jl + rc) * ld + swzl;
        lBe[i] = 8192 + je * 512;
        lBl[i] = 8192 + jl * 512;
    }

    // prologue: tile0 full (8/wave), tile1 A+Bearly (6/wave); vmcnt(6)=t0 done
#pragma unroll
    for (int i = 0; i < 4; i++) async16(gA[i], sm + lA[i]);
#pragma unroll
    for (int i = 0; i < 2; i++) async16(gBe[i], sm + lBe[i]);
#pragma unroll
    for (int i = 0; i < 2; i++) async16(gBl[i], sm + lBl[i]);
#pragma unroll
    for (int i = 0; i < 4; i++) async16(gA[i] + 64, sm + 16384 + lA[i]);
#pragma unroll
    for (int i = 0; i < 2; i++) async16(gBe[i] + 64, sm + 16384 + lBe[i]);
    asm volatile("s_waitcnt vmcnt(6)" ::: "memory");
    BAR();

#pragma unroll 2
    for (int t = 0; t < NT; ++t) {
        const _Float16* As = sm + (t & 1) * 16384;
        const _Float16* Bs = As + 8192;
        f16x8 af[2][4], bf[4];

        // ---- P0: read A(all) + B nf=0; stage t+1's B-late into other buffer
#pragma unroll
        for (int m = 0; m < 2; m++)
#pragma unroll
            for (int s = 0; s < 4; s++) {
                int ra = wm * 64 + m * 32 + fr32;
                af[m][s] = *(const f16x8*)&As[ra * 64 + ((((2 * s + q2) ^ fx ^ rq)) * 8)];
            }
#pragma unroll
        for (int s = 0; s < 4; s++) {
            int rb = wn * 64 + fr32;
            bf[s] = *(const f16x8*)&Bs[rb * 64 + ((((2 * s + q2) ^ fx ^ rq)) * 8)];
        }
        if (t + 1 < NT) {
            _Float16* nb = sm + ((t + 1) & 1) * 16384;
#pragma unroll
            for (int i = 0; i < 2; i++)
                async16(gBl[i] + (t + 1) * 64, nb + lBl[i]);
        }
        BAR(); LGKM0();
        if (WITH_RS) {
#pragma unroll
            for (int m = 0; m < 2; m++)
#pragma unroll
                for (int s = 0; s < 4; s++) rs[m] = frag_sum8(af[m][s], rs[m]);
        }
        __builtin_amdgcn_s_setprio(1);
#pragma unroll
        for (int s = 0; s < 4; s++)
#pragma unroll
            for (int m = 0; m < 2; m++)
                acc[m][0] = MFMA32(af[m][s], bf[s], acc[m][0]);
        __builtin_amdgcn_s_setprio(0);
        BAR();

        // ---- P1: read B nf=1; stage t+2's A+B-early into this buffer
#pragma unroll
        for (int s = 0; s < 4; s++) {
            int rb = wn * 64 + 32 + fr32;
            bf[s] = *(const f16x8*)&Bs[rb * 64 + ((((2 * s + q2) ^ fx ^ rq)) * 8)];
        }
        if (t + 2 < NT) {
            _Float16* stg = sm + (t & 1) * 16384;
            const int k2 = (t + 2) * 64;
#pragma unroll
            for (int i = 0; i < 4; i++) async16(gA[i] + k2, stg + lA[i]);
#pragma unroll
            for (int i = 0; i < 2; i++) async16(gBe[i] + k2, stg + lBe[i]);
            asm volatile("s_waitcnt vmcnt(6)" ::: "memory");   // t+1 landed
        } else {
            asm volatile("s_waitcnt vmcnt(0)" ::: "memory");   // tail drain
        }
        BAR(); LGKM0();
        __builtin_amdgcn_s_setprio(1);
#pragma unroll
        for (int s = 0; s < 4; s++)
#pragma unroll
            for (int m = 0; m < 2; m++)
                acc[m][1] = MFMA32(af[m][s], bf[s], acc[m][1]);
        __builtin_amdgcn_s_setprio(0);
        BAR();
    }
}

// ---------------- 1. prep: x->fp16 and W->fp16 W^T --------------------------
__global__ __launch_bounds__(256) void prep(
    const float* __restrict__ x,
    const float* __restrict__ Wq, const float* __restrict__ Wk,
    const float* __restrict__ Wv,
    _Float16* __restrict__ Xh,
    _Float16* __restrict__ WqT, _Float16* __restrict__ WkT,
    _Float16* __restrict__ WvT)
{
    const int bid = blockIdx.x;
    if (bid < 8192) {                       // convert x: 8.4M elems / 1024
        int i = (bid * 256 + threadIdx.x) * 4;
        float4 v = *(const float4*)(x + i);
        f16x4 h;
        h.x = (_Float16)v.x; h.y = (_Float16)v.y;
        h.z = (_Float16)v.z; h.w = (_Float16)v.w;
        *(f16x4*)&Xh[i] = h;
    } else {                                // transpose W: 3 x 1024 blocks
        int t = bid - 8192;
        int z = t >> 10;
        const float* W = (z == 0) ? Wq : (z == 1) ? Wk : Wv;
        _Float16* Wt   = (z == 0) ? WqT : (z == 1) ? WkT : WvT;
        int idx = (t & 1023) * 256 + threadIdx.x;
        int n = idx >> 9, k = idx & 511;
        Wt[idx] = (_Float16)W[k * 512 + n];
    }
}

// ---------------- 2. projections --------------------------------------------
// grid (x=128, y=4, z=3), 256 thr. z<2: row0=bx*128 (X rows), col0=by*128.
// z=2: row0=by*128 (d), col0=bx*128 (s_global). 4 col-blocks of one row-tile
// have bids differing by 128 (=0 mod 8) -> same XCD -> X rows fetched once.
__global__ __launch_bounds__(256, 2) void proj_mfma(
    const _Float16* __restrict__ Xh,
    const _Float16* __restrict__ WqT, const float* __restrict__ bq,
    const _Float16* __restrict__ WkT, const float* __restrict__ bk,
    const _Float16* __restrict__ WvT, const float* __restrict__ bv,
    _Float16* __restrict__ Qh, _Float16* __restrict__ Kh,
    _Float16* __restrict__ Vt)
{
    __shared__ __align__(16) _Float16 smem[2 * 16384];
    const int z = blockIdx.z;
    f32x16 acc[2][2] = {};
    float rs_unused[2];

    const int lane = threadIdx.x & 63, wave = threadIdx.x >> 6;
    const int wm = wave >> 1, wn = wave & 1;
    const int fr32 = lane & 31, q2 = lane >> 5;

    if (z < 2) {
        const _Float16* Wt = (z == 0) ? WqT : WkT;
        const float* bias  = (z == 0) ? bq : bk;
        _Float16* P        = (z == 0) ? Qh : Kh;
        const float sc     = (z == 0) ? 0.04419417382415922f : 1.0f;
        const int row0 = blockIdx.x * 128, col0 = blockIdx.y * 128;
        core128sq<8, false>(Xh, Wt, 512, row0, col0, smem, acc, rs_unused);
#pragma unroll
        for (int mf = 0; mf < 2; mf++)
#pragma unroll
            for (int nf = 0; nf < 2; nf++) {
                int col = col0 + wn * 64 + nf * 32 + fr32;
                float bb = bias[col];
#pragma unroll
                for (int reg = 0; reg < 16; reg++) {
                    int row = row0 + wm * 64 + mf * 32 +
                              (reg & 3) + 8 * (reg >> 2) + 4 * q2;
                    P[(size_t)row * 512 + col] = (_Float16)((acc[mf][nf][reg] + bb) * sc);
                }
            }
    } else {
        // transposed V: out(row=d, col=s_global) = sum_k WvT[d][k] * Xh[s][k]
        const int row0 = blockIdx.y * 128;   // d (M=512)
        const int col0 = blockIdx.x * 128;   // s_global (N=16384)
        core128sq<8, false>(WvT, Xh, 512, row0, col0, smem, acc, rs_unused);
#pragma unroll
        for (int mf = 0; mf < 2; mf++)
#pragma unroll
            for (int nf = 0; nf < 2; nf++) {
                int col = col0 + wn * 64 + nf * 32 + fr32;   // s_global
                size_t obase = (size_t)(col >> 11) * (512 * 2048) + (col & 2047);
#pragma unroll
                for (int reg = 0; reg < 16; reg++) {
                    int row = row0 + wm * 64 + mf * 32 +
                              (reg & 3) + 8 * (reg >> 2) + 4 * q2;  // d
                    Vt[obase + (size_t)row * 2048] = (_Float16)(acc[mf][nf][reg] + bv[row]);
                }
            }
    }
}

// ---------------- 3. scores: P = exp(Q.K^T) (unnormalized) ------------------
// grid 2048: batch = bid&7 (XCD pin: Q[b]+K[b]=4MB=one XCD L2), col fastest.
__global__ __launch_bounds__(256, 2) void scores_mfma(
    const _Float16* __restrict__ Qh, const _Float16* __restrict__ Kh,
    _Float16* __restrict__ Sh)
{
    __shared__ __align__(16) _Float16 smem[2 * 16384];
    const int bid = blockIdx.x;
    const int b   = bid & 7;
    const int rem = bid >> 3;
    const int col0 = (rem & 15) * 128;
    const int row0 = (rem >> 4) * 128;

    const _Float16* A = Qh + (size_t)b * 2048 * 512;
    const _Float16* B = Kh + (size_t)b * 2048 * 512;
    _Float16* S = Sh + (size_t)b * 2048 * 2048;

    f32x16 acc[2][2] = {};
    float rs_unused[2];

    core128sq<8, false>(A, B, 512, row0, col0, smem, acc, rs_unused);

    const int lane = threadIdx.x & 63, wave = threadIdx.x >> 6;
    const int wm = wave >> 1, wn = wave & 1;
    const int fr32 = lane & 31, q2 = lane >> 5;
#pragma unroll
    for (int mf = 0; mf < 2; mf++)
#pragma unroll
        for (int nf = 0; nf < 2; nf++) {
            int col = col0 + wn * 64 + nf * 32 + fr32;
#pragma unroll
            for (int reg = 0; reg < 16; reg++) {
                int row = row0 + wm * 64 + mf * 32 +
                          (reg & 3) + 8 * (reg >> 2) + 4 * q2;
                S[(size_t)row * 2048 + col] = (_Float16)__expf(acc[mf][nf][reg]);
            }
        }
}

// ---------------- 4. out = (P.V) * mask / rowsum(P) -------------------------
// grid 512: batch = bid&7 (XCD pin: P[b] streams through one XCD L2,
// V[b]=2MB resident), col fastest -> the 4 col-blocks of one row-group run
// adjacently and share P rows.
__global__ __launch_bounds__(256, 2) void av_mfma(
    const _Float16* __restrict__ Sh, const _Float16* __restrict__ Vt,
    const float* __restrict__ mask, float* __restrict__ out)
{
    __shared__ __align__(16) _Float16 smem[2 * 16384];
    const int bid = blockIdx.x;
    const int b   = bid & 7;
    const int rem = bid >> 3;
    const int col0 = (rem & 3) * 128;
    const int row0 = (rem >> 2) * 128;

    const _Float16* A = Sh + (size_t)b * 2048 * 2048;
    const _Float16* B = Vt + (size_t)b * 512 * 2048;
    float* O = out + (size_t)b * 2048 * 512;
    const float* mk = mask + (size_t)b * 2048;

    f32x16 acc[2][2] = {};
    float rs[2] = {0.f, 0.f};

    core128sq<32, true>(A, B, 2048, row0, col0, smem, acc, rs);

    const int lane = threadIdx.x & 63, wave = threadIdx.x >> 6;
    const int wm = wave >> 1, wn = wave & 1;
    const int fr32 = lane & 31, q2 = lane >> 5;

    // rs[mf]: partial rowsum of row (wm*64+mf*32+fr32) over this lane's
    // k-halves (bit3 of k == q2); xor-32 butterfly completes it.
#pragma unroll
    for (int mf = 0; mf < 2; mf++) rs[mf] += __shfl_xor(rs[mf], 32, 64);
    __syncthreads();                       // all waves out of the GEMM loop
    float* l_s = (float*)smem;             // alias dead staging LDS
    if (wn == 0 && lane < 32) {            // waves 0 (wm=0), 2 (wm=1)
#pragma unroll
        for (int mf = 0; mf < 2; mf++) l_s[wm * 64 + mf * 32 + lane] = rs[mf];
    }
    __syncthreads();

#pragma unroll
    for (int mf = 0; mf < 2; mf++)
#pragma unroll
        for (int nf = 0; nf < 2; nf++) {
            int col = col0 + wn * 64 + nf * 32 + fr32;
#pragma unroll
            for (int reg = 0; reg < 16; reg++) {
                int lrow = wm * 64 + mf * 32 + (reg & 3) + 8 * (reg >> 2) + 4 * q2;
                int row = row0 + lrow;
                float s = mk[row] / l_s[lrow];
                O[(size_t)row * 512 + col] = acc[mf][nf][reg] * s;
            }
        }
}

extern "C" void kernel_launch(void* const* d_in, const int* in_sizes, int n_in,
                              void* d_out, int out_size, void* d_ws, size_t ws_size,
                              hipStream_t stream) {
    const float* x    = (const float*)d_in[0];
    const float* mask = (const float*)d_in[1];
    const float* Wq   = (const float*)d_in[2];
    const float* bq   = (const float*)d_in[3];
    const float* Wk   = (const float*)d_in[4];
    const float* bk   = (const float*)d_in[5];
    const float* Wv   = (const float*)d_in[6];
    const float* bv   = (const float*)d_in[7];
    float* out = (float*)d_out;

    const size_t BSD = (size_t)8 * 2048 * 512;       // 8.4M halves
    _Float16* base = (_Float16*)d_ws;
    _Float16* Qh  = base;
    _Float16* Kh  = Qh + BSD;
    _Float16* Vt  = Kh + BSD;                         // [b][d][s]
    _Float16* WqT = Vt + BSD;
    _Float16* WkT = WqT + 512 * 512;
    _Float16* WvT = WkT + 512 * 512;
    _Float16* Xh  = WvT + 512 * 512;
    _Float16* Sh  = Xh;                               // Xh dead after proj

    prep<<<dim3(8192 + 3 * 1024), dim3(256), 0, stream>>>(
        x, Wq, Wk, Wv, Xh, WqT, WkT, WvT);
    proj_mfma<<<dim3(128, 4, 3), dim3(256), 0, stream>>>(
        Xh, WqT, bq, WkT, bk, WvT, bv, Qh, Kh, Vt);
    scores_mfma<<<dim3(2048), dim3(256), 0, stream>>>(Qh, Kh, Sh);
    av_mfma<<<dim3(512), dim3(256), 0, stream>>>(Sh, Vt, mask, out);
}